// Round 2
// baseline (625.727 us; speedup 1.0000x reference)
//
#include <hip/hip_runtime.h>
#include <stdint.h>

#define NPTS   8192
#define NROWS  (NPTS * 16)
#define SLOPE  0.01f
#define BN_EPS 1e-5f

// ---- workspace layout (bytes) ----
#define OFF_Q      0u          // 8192x128 f32  (fea_last @ Wq^T + bq)
#define OFF_KP     4194304u    // 8192x128 f32
#define OFF_VP     8388608u    // 8192x128 f32
#define OFF_WT     12582912u   // 4 x 128x128 f32 transposed: WqT WkT WvT WlT (c-major: WT[c*128+o] = W[o*128+c])
#define OFF_XYZT   12845056u   // 6 x 8192 f32: xi yi zi | xl yl zl
#define OFF_IDX    13041664u   // 131072 i32 (8192 x 16 neighbor ids)
#define OFF_STATS  13565952u   // 4864 f32: stats1[256] bn1[256] stats2[16*256] bn2[256]
#define OFF_BIG    13585408u   // candD(8MB)+candI(8MB), later aliased by Y bf16 (33.5MB)
#define WS_NEED    47139840u

__device__ __forceinline__ unsigned int pack_bf2(float lo, float hi) {
  unsigned int a = __float_as_uint(lo);
  unsigned int b = __float_as_uint(hi);
  unsigned int ra = (a + 0x7fffu + ((a >> 16) & 1u)) >> 16;           // RNE bf16 of lo
  unsigned int rb = (b + 0x7fffu + ((b >> 16) & 1u)) & 0xffff0000u;   // RNE bf16 of hi in high half
  return ra | rb;
}
__device__ __forceinline__ void unpack2(unsigned int u, float& lo, float& hi) {
  lo = __uint_as_float(u << 16);
  hi = __uint_as_float(u & 0xffff0000u);
}
__device__ __forceinline__ float bf2f(unsigned short u) {
  return __uint_as_float(((unsigned int)u) << 16);
}

// ---------------- prep: transpose xyz + weights, zero stats ----------------
__global__ __launch_bounds__(256) void k_prep(const float* __restrict__ xyz_i,
                                              const float* __restrict__ xyz_last,
                                              const float* __restrict__ Wq,
                                              const float* __restrict__ Wk,
                                              const float* __restrict__ Wv,
                                              const float* __restrict__ Wl,
                                              float* __restrict__ xyzT,
                                              float* __restrict__ WT,
                                              float* __restrict__ stats_zero) {
  int t = blockIdx.x * 256 + threadIdx.x;   // 16384 threads
  if (t < NPTS) {
    xyzT[0 * NPTS + t] = xyz_i[t * 3 + 0];
    xyzT[1 * NPTS + t] = xyz_i[t * 3 + 1];
    xyzT[2 * NPTS + t] = xyz_i[t * 3 + 2];
    xyzT[3 * NPTS + t] = xyz_last[t * 3 + 0];
    xyzT[4 * NPTS + t] = xyz_last[t * 3 + 1];
    xyzT[5 * NPTS + t] = xyz_last[t * 3 + 2];
  }
  {
    int o = t >> 7, c = t & 127;
    WT[0 * 16384 + c * 128 + o] = Wq[t];
    WT[1 * 16384 + c * 128 + o] = Wk[t];
    WT[2 * 16384 + c * 128 + o] = Wv[t];
    WT[3 * 16384 + c * 128 + o] = Wl[t];
  }
  if (t < 4864) stats_zero[t] = 0.f;
}

// ---------------- projections: Out = A @ W^T + b (8192x128 @ 128x128) ----------------
// 64 rows/block, 256 threads, per-thread 4x8 tile, bf16 operands in LDS, f32 accum.
__global__ __launch_bounds__(256) void k_proj(const float* __restrict__ fea_i,
                                              const float* __restrict__ fea_last,
                                              const float* __restrict__ WT,
                                              const float* __restrict__ bq,
                                              const float* __restrict__ bk,
                                              const float* __restrict__ bv,
                                              float* __restrict__ Qo,
                                              float* __restrict__ Kpo,
                                              float* __restrict__ Vpo) {
  const int z = blockIdx.y;
  const float* A    = (z == 0) ? fea_last : fea_i;
  const float* WTz  = WT + z * 16384;
  const float* bias = (z == 0) ? bq : ((z == 1) ? bk : bv);
  float* Out        = (z == 0) ? Qo : ((z == 1) ? Kpo : Vpo);

  __shared__ unsigned short aT[128 * 72];    // [c][r], r<64, pad 72
  __shared__ unsigned short wT[128 * 128];   // [c][o] bf16
  const int t = threadIdx.x;
  const int rowbase = blockIdx.x * 64;
  {
    const int c = t & 127, half = t >> 7;
    #pragma unroll
    for (int i = 0; i < 16; ++i) {
      const int r = half * 32 + i * 2;
      float v0 = A[(size_t)(rowbase + r) * 128 + c];
      float v1 = A[(size_t)(rowbase + r + 1) * 128 + c];
      *(unsigned int*)&aT[c * 72 + r] = pack_bf2(v0, v1);
    }
    #pragma unroll
    for (int i = 0; i < 32; ++i) {
      const int e = i * 512 + t * 2;
      *(unsigned int*)&wT[e] = pack_bf2(WTz[e], WTz[e + 1]);
    }
  }
  __syncthreads();
  const int cg = t & 15, rg = t >> 4;
  const int p0 = cg * 8, r0 = rg * 4;
  float acc[4][8];
  #pragma unroll
  for (int i = 0; i < 4; ++i)
    #pragma unroll
    for (int j = 0; j < 8; ++j) acc[i][j] = 0.f;

  #pragma unroll 4
  for (int c = 0; c < 128; ++c) {
    uint2 au = *(const uint2*)&aT[c * 72 + r0];
    uint4 bu = *(const uint4*)&wT[c * 128 + p0];
    float a0, a1, a2, a3, b[8];
    unpack2(au.x, a0, a1); unpack2(au.y, a2, a3);
    unpack2(bu.x, b[0], b[1]); unpack2(bu.y, b[2], b[3]);
    unpack2(bu.z, b[4], b[5]); unpack2(bu.w, b[6], b[7]);
    #pragma unroll
    for (int j = 0; j < 8; ++j) {
      acc[0][j] = fmaf(a0, b[j], acc[0][j]);
      acc[1][j] = fmaf(a1, b[j], acc[1][j]);
      acc[2][j] = fmaf(a2, b[j], acc[2][j]);
      acc[3][j] = fmaf(a3, b[j], acc[3][j]);
    }
  }
  float bs[8];
  #pragma unroll
  for (int j = 0; j < 8; ++j) bs[j] = bias[p0 + j];
  #pragma unroll
  for (int i = 0; i < 4; ++i) {
    const int row = rowbase + r0 + i;
    float4 o0, o1;
    o0.x = acc[i][0] + bs[0]; o0.y = acc[i][1] + bs[1]; o0.z = acc[i][2] + bs[2]; o0.w = acc[i][3] + bs[3];
    o1.x = acc[i][4] + bs[4]; o1.y = acc[i][5] + bs[5]; o1.z = acc[i][6] + bs[6]; o1.w = acc[i][7] + bs[7];
    *(float4*)&Out[(size_t)row * 128 + p0]     = o0;
    *(float4*)&Out[(size_t)row * 128 + p0 + 4] = o1;
  }
}

// ---------------- KNN pass 1: per-(query,slice) top-16 via sorted insertion ----------------
__global__ __launch_bounds__(256) void k_knn_part(const float* __restrict__ xyzT,
                                                  float* __restrict__ candD,
                                                  int* __restrict__ candI) {
  const int T = blockIdx.x * 256 + threadIdx.x;   // 131072 threads
  const int q = T & (NPTS - 1);
  const int slice = T >> 13;                      // 16 slices of 512 points
  const float qx = xyzT[3 * NPTS + q];
  const float qy = xyzT[4 * NPTS + q];
  const float qz = xyzT[5 * NPTS + q];
  const float* xt = xyzT;
  const float* yt = xyzT + NPTS;
  const float* zt = xyzT + 2 * NPTS;

  float d[16]; int pi[16];
  #pragma unroll
  for (int j = 0; j < 16; ++j) { d[j] = 3.4e38f; pi[j] = 0; }

  const int base = slice * 512;
  for (int jj = 0; jj < 512; ++jj) {
    const int p = base + jj;
    float dx = qx - xt[p], dy = qy - yt[p], dz = qz - zt[p];
    float dd = fmaf(dx, dx, fmaf(dy, dy, dz * dz));
    if (dd < d[15]) {            // strict < : earlier (lower) index wins ties
      #pragma unroll
      for (int s = 15; s >= 1; --s) {
        bool cm1 = dd < d[s - 1];
        bool cs  = dd < d[s];
        d[s]  = cm1 ? d[s - 1]  : (cs ? dd : d[s]);
        pi[s] = cm1 ? pi[s - 1] : (cs ? p  : pi[s]);
      }
      bool c0 = dd < d[0];
      d[0]  = c0 ? dd : d[0];
      pi[0] = c0 ? p  : pi[0];
    }
  }
  #pragma unroll
  for (int j = 0; j < 16; ++j) {
    candD[(size_t)(slice * 16 + j) * NPTS + q] = d[j];
    candI[(size_t)(slice * 16 + j) * NPTS + q] = pi[j];
  }
}

// ---------------- KNN pass 2: merge 16 slices, lex (dist,idx) order ----------------
__global__ __launch_bounds__(256) void k_knn_merge(const float* __restrict__ candD,
                                                   const int* __restrict__ candI,
                                                   int* __restrict__ idxo) {
  const int q = blockIdx.x * 256 + threadIdx.x;   // 8192 threads
  unsigned long long key[16];
  #pragma unroll
  for (int j = 0; j < 16; ++j) key[j] = ~0ull;
  for (int s = 0; s < 256; ++s) {
    float dv = candD[(size_t)s * NPTS + q];
    unsigned int pv = (unsigned int)candI[(size_t)s * NPTS + q];
    unsigned long long kk = ((unsigned long long)__float_as_uint(dv) << 32) | pv;
    if (kk < key[15]) {
      #pragma unroll
      for (int u = 15; u >= 1; --u) {
        bool cm1 = kk < key[u - 1];
        bool cs  = kk < key[u];
        key[u] = cm1 ? key[u - 1] : (cs ? kk : key[u]);
      }
      key[0] = (kk < key[0]) ? kk : key[0];
    }
  }
  #pragma unroll
  for (int j = 0; j < 16; ++j) idxo[q * 16 + j] = (int)(key[j] & 0xffffffffull);
}

// ---------------- stats1: per-channel sum/sumsq of w = Q[n] - Kp[idx] ----------------
__global__ __launch_bounds__(256) void k_stats1(const float* __restrict__ Q,
                                                const float* __restrict__ Kp,
                                                const int* __restrict__ idx,
                                                float* __restrict__ stats1) {
  const int t = threadIdx.x;
  const int o = t & 127, h = t >> 7;
  float s = 0.f, q2 = 0.f;
  const int base = blockIdx.x * 512;
  for (int i = 0; i < 256; ++i) {
    const int row = base + i * 2 + h;
    const int n = row >> 4;
    const int pid = idx[row];
    float w = Q[(size_t)n * 128 + o] - Kp[(size_t)pid * 128 + o];
    s += w; q2 += w * w;
  }
  __shared__ float rs[256], rq[256];
  rs[t] = s; rq[t] = q2;
  __syncthreads();
  if (t < 128) {
    atomicAdd(&stats1[o],       rs[t] + rs[t + 128]);
    atomicAdd(&stats1[128 + o], rq[t] + rq[t + 128]);
  }
}

// ---------------- BN finalize: scale/shift from (sum,sumsq) ----------------
__global__ void k_bnfin(const float* __restrict__ stats, int nrep, float invM,
                        const float* __restrict__ gamma, const float* __restrict__ beta,
                        float* __restrict__ bn) {
  const int o = threadIdx.x;  // 128
  float s = 0.f, q = 0.f;
  for (int r = 0; r < nrep; ++r) { s += stats[r * 256 + o]; q += stats[r * 256 + 128 + o]; }
  float mean = s * invM;
  float var  = fmaf(-mean, mean, q * invM);     // biased variance
  float sc = gamma[o] * rsqrtf(var + BN_EPS);
  bn[o]       = sc;
  bn[128 + o] = fmaf(-mean, sc, beta[o]);
}

// ---------------- mid GEMM: y = leaky(bn1(w)) @ Wl^T + bl ; + BN2 stats; y -> bf16 ----------------
__global__ __launch_bounds__(256) void k_mid(const float* __restrict__ Q,
                                             const float* __restrict__ Kp,
                                             const int* __restrict__ idx,
                                             const float* __restrict__ WTl,
                                             const float* __restrict__ bl,
                                             const float* __restrict__ bn1,
                                             float* __restrict__ stats2,
                                             unsigned short* __restrict__ Y) {
  __shared__ unsigned short aT[128 * 72];
  __shared__ unsigned short wT[128 * 128];
  __shared__ float red[4 * 16 * 16];
  const int t = threadIdx.x;
  const int rowbase = blockIdx.x * 64;
  {
    const int c = t & 127, half = t >> 7;
    const float s1 = bn1[c], sh1 = bn1[128 + c];
    #pragma unroll
    for (int i = 0; i < 16; ++i) {
      const int r = half * 32 + i * 2;
      const int g0 = rowbase + r, g1 = g0 + 1;
      const int n0 = g0 >> 4, n1 = g1 >> 4;
      const int pa = idx[g0], pb = idx[g1];
      float w0 = Q[(size_t)n0 * 128 + c] - Kp[(size_t)pa * 128 + c];
      float w1 = Q[(size_t)n1 * 128 + c] - Kp[(size_t)pb * 128 + c];
      float x0 = fmaf(w0, s1, sh1); x0 = (x0 >= 0.f) ? x0 : SLOPE * x0;
      float x1 = fmaf(w1, s1, sh1); x1 = (x1 >= 0.f) ? x1 : SLOPE * x1;
      *(unsigned int*)&aT[c * 72 + r] = pack_bf2(x0, x1);
    }
    #pragma unroll
    for (int i = 0; i < 32; ++i) {
      const int e = i * 512 + t * 2;
      *(unsigned int*)&wT[e] = pack_bf2(WTl[e], WTl[e + 1]);
    }
  }
  __syncthreads();
  const int cg = t & 15, rg = t >> 4;
  const int p0 = cg * 8, r0 = rg * 4;
  float acc[4][8];
  #pragma unroll
  for (int i = 0; i < 4; ++i)
    #pragma unroll
    for (int j = 0; j < 8; ++j) acc[i][j] = 0.f;

  #pragma unroll 4
  for (int c = 0; c < 128; ++c) {
    uint2 au = *(const uint2*)&aT[c * 72 + r0];
    uint4 bu = *(const uint4*)&wT[c * 128 + p0];
    float a0, a1, a2, a3, b[8];
    unpack2(au.x, a0, a1); unpack2(au.y, a2, a3);
    unpack2(bu.x, b[0], b[1]); unpack2(bu.y, b[2], b[3]);
    unpack2(bu.z, b[4], b[5]); unpack2(bu.w, b[6], b[7]);
    #pragma unroll
    for (int j = 0; j < 8; ++j) {
      acc[0][j] = fmaf(a0, b[j], acc[0][j]);
      acc[1][j] = fmaf(a1, b[j], acc[1][j]);
      acc[2][j] = fmaf(a2, b[j], acc[2][j]);
      acc[3][j] = fmaf(a3, b[j], acc[3][j]);
    }
  }
  float bs[8];
  #pragma unroll
  for (int j = 0; j < 8; ++j) bs[j] = bl[p0 + j];
  float ssum[8], sqq[8];
  #pragma unroll
  for (int j = 0; j < 8; ++j) { ssum[j] = 0.f; sqq[j] = 0.f; }
  #pragma unroll
  for (int i = 0; i < 4; ++i) {
    float zv[8];
    #pragma unroll
    for (int j = 0; j < 8; ++j) { zv[j] = acc[i][j] + bs[j]; ssum[j] += zv[j]; sqq[j] += zv[j] * zv[j]; }
    uint4 st;
    st.x = pack_bf2(zv[0], zv[1]); st.y = pack_bf2(zv[2], zv[3]);
    st.z = pack_bf2(zv[4], zv[5]); st.w = pack_bf2(zv[6], zv[7]);
    *(uint4*)&Y[(size_t)(rowbase + r0 + i) * 128 + p0] = st;
  }
  // reduce stats over the 4 rgrps within each wave (lanes xor 16,32), then across waves via LDS
  #pragma unroll
  for (int j = 0; j < 8; ++j) {
    ssum[j] += __shfl_xor(ssum[j], 16); ssum[j] += __shfl_xor(ssum[j], 32);
    sqq[j]  += __shfl_xor(sqq[j], 16);  sqq[j]  += __shfl_xor(sqq[j], 32);
  }
  const int lane = t & 63, wave = t >> 6;
  if (lane < 16) {
    #pragma unroll
    for (int j = 0; j < 8; ++j) {
      red[(wave * 16 + lane) * 16 + j]     = ssum[j];
      red[(wave * 16 + lane) * 16 + 8 + j] = sqq[j];
    }
  }
  __syncthreads();
  {
    const int cg2 = t >> 4, v = t & 15;
    float tot = red[(0 * 16 + cg2) * 16 + v] + red[(1 * 16 + cg2) * 16 + v]
              + red[(2 * 16 + cg2) * 16 + v] + red[(3 * 16 + cg2) * 16 + v];
    const int p = cg2 * 8 + (v & 7);
    const int stat = v >> 3;
    atomicAdd(&stats2[(blockIdx.x & 15) * 256 + stat * 128 + p], tot);
  }
}

// ---------------- epilogue: BN2+leaky -> softmax over K -> weighted V gather ----------------
__global__ __launch_bounds__(128) void k_epi(const unsigned short* __restrict__ Y,
                                             const float* __restrict__ Vp,
                                             const int* __restrict__ idx,
                                             const float* __restrict__ bn2,
                                             float* __restrict__ out) {
  const int n = blockIdx.x;
  const int p = threadIdx.x;
  const float s2 = bn2[p], sh2 = bn2[128 + p];
  float z[16];
  #pragma unroll
  for (int k = 0; k < 16; ++k) {
    float yv = bf2f(Y[(size_t)(n * 16 + k) * 128 + p]);
    float v = fmaf(yv, s2, sh2);
    z[k] = (v >= 0.f) ? v : SLOPE * v;
  }
  float m = z[0];
  #pragma unroll
  for (int k = 1; k < 16; ++k) m = fmaxf(m, z[k]);
  float acc = 0.f, denom = 0.f;
  #pragma unroll
  for (int k = 0; k < 16; ++k) {
    float e = __expf(z[k] - m);
    denom += e;
    const int pid = idx[n * 16 + k];
    acc = fmaf(e, Vp[(size_t)pid * 128 + p], acc);
  }
  out[(size_t)n * 128 + p] = acc / denom;
}

extern "C" void kernel_launch(void* const* d_in, const int* in_sizes, int n_in,
                              void* d_out, int out_size, void* d_ws, size_t ws_size,
                              hipStream_t stream) {
  const float* fea_i    = (const float*)d_in[0];
  const float* fea_last = (const float*)d_in[1];
  const float* xyz_i    = (const float*)d_in[2];
  const float* xyz_last = (const float*)d_in[3];
  // d_in[4] = batch (single batch, unused)
  const float* Wq = (const float*)d_in[5];
  const float* bq = (const float*)d_in[6];
  const float* Wk = (const float*)d_in[7];
  const float* bk = (const float*)d_in[8];
  const float* Wv = (const float*)d_in[9];
  const float* bv = (const float*)d_in[10];
  const float* g1 = (const float*)d_in[11];
  const float* b1 = (const float*)d_in[12];
  const float* Wl = (const float*)d_in[13];
  const float* bl = (const float*)d_in[14];
  const float* g2 = (const float*)d_in[15];
  const float* b2 = (const float*)d_in[16];

  if (ws_size < (size_t)WS_NEED) return;  // need ~45 MiB scratch

  char* ws = (char*)d_ws;
  float* Q      = (float*)(ws + OFF_Q);
  float* Kp     = (float*)(ws + OFF_KP);
  float* Vp     = (float*)(ws + OFF_VP);
  float* WT     = (float*)(ws + OFF_WT);
  float* xyzT   = (float*)(ws + OFF_XYZT);
  int*   idxb   = (int*)  (ws + OFF_IDX);
  float* stats1 = (float*)(ws + OFF_STATS);
  float* bn1    = stats1 + 256;
  float* stats2 = stats1 + 512;
  float* bn2    = stats1 + 512 + 4096;
  float* candD  = (float*)(ws + OFF_BIG);
  int*   candI  = (int*)  (ws + OFF_BIG + 8388608u);
  unsigned short* Y = (unsigned short*)(ws + OFF_BIG);  // aliases cand buffers (dead by then)

  k_prep<<<64, 256, 0, stream>>>(xyz_i, xyz_last, Wq, Wk, Wv, Wl, xyzT, WT, stats1);
  k_proj<<<dim3(128, 3), 256, 0, stream>>>(fea_i, fea_last, WT, bq, bk, bv, Q, Kp, Vp);
  k_knn_part<<<512, 256, 0, stream>>>(xyzT, candD, candI);
  k_knn_merge<<<32, 256, 0, stream>>>(candD, candI, idxb);
  k_stats1<<<256, 256, 0, stream>>>(Q, Kp, idxb, stats1);
  k_bnfin<<<1, 128, 0, stream>>>(stats1, 1, 1.f / (float)NROWS, g1, b1, bn1);
  k_mid<<<2048, 256, 0, stream>>>(Q, Kp, idxb, WT + 3 * 16384, bl, bn1, stats2, Y);
  k_bnfin<<<1, 128, 0, stream>>>(stats2, 16, 1.f / (float)NROWS, g2, b2, bn2);
  k_epi<<<8192, 128, 0, stream>>>(Y, Vp, idxb, bn2, (float*)d_out);
}

// Round 3
// 624.782 us; speedup vs baseline: 1.0015x; 1.0015x over previous
//
#include <hip/hip_runtime.h>
#include <stdint.h>

#define NPTS   8192
#define NROWS  (NPTS * 16)
#define SLOPE  0.01f
#define BN_EPS 1e-5f

// ---- workspace layout (bytes) ----
#define OFF_Q      0u          // 8192x128 f32  (fea_last @ Wq^T + bq)
#define OFF_KP     4194304u    // 8192x128 f32
#define OFF_VP     8388608u    // 8192x128 f32
#define OFF_WT     12582912u   // 4 x 128x128 f32 transposed: WqT WkT WvT WlT (c-major: WT[c*128+o] = W[o*128+c])
#define OFF_XYZT   12845056u   // 6 x 8192 f32: xi yi zi | xl yl zl
#define OFF_IDX    13041664u   // 131072 i32 (8192 x 16 neighbor ids)
#define OFF_STATS  13565952u   // 4864 f32: stats1[256] bn1[256] stats2[16*256] bn2[256]
#define OFF_BIG    13585408u   // candD(8MB)+candI(8MB), later aliased by Y bf16 (33.5MB)
#define WS_NEED    47139840u

__device__ __forceinline__ unsigned int pack_bf2(float lo, float hi) {
  unsigned int a = __float_as_uint(lo);
  unsigned int b = __float_as_uint(hi);
  unsigned int ra = (a + 0x7fffu + ((a >> 16) & 1u)) >> 16;           // RNE bf16 of lo
  unsigned int rb = (b + 0x7fffu + ((b >> 16) & 1u)) & 0xffff0000u;   // RNE bf16 of hi in high half
  return ra | rb;
}
__device__ __forceinline__ void unpack2(unsigned int u, float& lo, float& hi) {
  lo = __uint_as_float(u << 16);
  hi = __uint_as_float(u & 0xffff0000u);
}
__device__ __forceinline__ float bf2f(unsigned short u) {
  return __uint_as_float(((unsigned int)u) << 16);
}

// ---------------- prep: transpose xyz + weights, zero stats ----------------
__global__ __launch_bounds__(256) void k_prep(const float* __restrict__ xyz_i,
                                              const float* __restrict__ xyz_last,
                                              const float* __restrict__ Wq,
                                              const float* __restrict__ Wk,
                                              const float* __restrict__ Wv,
                                              const float* __restrict__ Wl,
                                              float* __restrict__ xyzT,
                                              float* __restrict__ WT,
                                              float* __restrict__ stats_zero) {
  int t = blockIdx.x * 256 + threadIdx.x;   // 16384 threads
  if (t < NPTS) {
    xyzT[0 * NPTS + t] = xyz_i[t * 3 + 0];
    xyzT[1 * NPTS + t] = xyz_i[t * 3 + 1];
    xyzT[2 * NPTS + t] = xyz_i[t * 3 + 2];
    xyzT[3 * NPTS + t] = xyz_last[t * 3 + 0];
    xyzT[4 * NPTS + t] = xyz_last[t * 3 + 1];
    xyzT[5 * NPTS + t] = xyz_last[t * 3 + 2];
  }
  {
    int o = t >> 7, c = t & 127;
    WT[0 * 16384 + c * 128 + o] = Wq[t];
    WT[1 * 16384 + c * 128 + o] = Wk[t];
    WT[2 * 16384 + c * 128 + o] = Wv[t];
    WT[3 * 16384 + c * 128 + o] = Wl[t];
  }
  if (t < 4864) stats_zero[t] = 0.f;
}

// ---------------- projections: Out = A @ W^T + b (8192x128 @ 128x128) ----------------
// 64 rows/block, 256 threads, per-thread 4x8 tile, bf16 operands in LDS, f32 accum.
__global__ __launch_bounds__(256) void k_proj(const float* __restrict__ fea_i,
                                              const float* __restrict__ fea_last,
                                              const float* __restrict__ WT,
                                              const float* __restrict__ bq,
                                              const float* __restrict__ bk,
                                              const float* __restrict__ bv,
                                              float* __restrict__ Qo,
                                              float* __restrict__ Kpo,
                                              float* __restrict__ Vpo) {
  const int z = blockIdx.y;
  const float* A    = (z == 0) ? fea_last : fea_i;
  const float* WTz  = WT + z * 16384;
  const float* bias = (z == 0) ? bq : ((z == 1) ? bk : bv);
  float* Out        = (z == 0) ? Qo : ((z == 1) ? Kpo : Vpo);

  __shared__ unsigned short aT[128 * 72];    // [c][r], r<64, pad 72
  __shared__ unsigned short wT[128 * 128];   // [c][o] bf16
  const int t = threadIdx.x;
  const int rowbase = blockIdx.x * 64;
  {
    const int c = t & 127, half = t >> 7;
    #pragma unroll
    for (int i = 0; i < 16; ++i) {
      const int r = half * 32 + i * 2;
      float v0 = A[(size_t)(rowbase + r) * 128 + c];
      float v1 = A[(size_t)(rowbase + r + 1) * 128 + c];
      *(unsigned int*)&aT[c * 72 + r] = pack_bf2(v0, v1);
    }
    #pragma unroll
    for (int i = 0; i < 32; ++i) {
      const int e = i * 512 + t * 2;
      *(unsigned int*)&wT[e] = pack_bf2(WTz[e], WTz[e + 1]);
    }
  }
  __syncthreads();
  const int cg = t & 15, rg = t >> 4;
  const int p0 = cg * 8, r0 = rg * 4;
  float acc[4][8];
  #pragma unroll
  for (int i = 0; i < 4; ++i)
    #pragma unroll
    for (int j = 0; j < 8; ++j) acc[i][j] = 0.f;

  #pragma unroll 4
  for (int c = 0; c < 128; ++c) {
    uint2 au = *(const uint2*)&aT[c * 72 + r0];
    uint4 bu = *(const uint4*)&wT[c * 128 + p0];
    float a0, a1, a2, a3, b[8];
    unpack2(au.x, a0, a1); unpack2(au.y, a2, a3);
    unpack2(bu.x, b[0], b[1]); unpack2(bu.y, b[2], b[3]);
    unpack2(bu.z, b[4], b[5]); unpack2(bu.w, b[6], b[7]);
    #pragma unroll
    for (int j = 0; j < 8; ++j) {
      acc[0][j] = fmaf(a0, b[j], acc[0][j]);
      acc[1][j] = fmaf(a1, b[j], acc[1][j]);
      acc[2][j] = fmaf(a2, b[j], acc[2][j]);
      acc[3][j] = fmaf(a3, b[j], acc[3][j]);
    }
  }
  float bs[8];
  #pragma unroll
  for (int j = 0; j < 8; ++j) bs[j] = bias[p0 + j];
  #pragma unroll
  for (int i = 0; i < 4; ++i) {
    const int row = rowbase + r0 + i;
    float4 o0, o1;
    o0.x = acc[i][0] + bs[0]; o0.y = acc[i][1] + bs[1]; o0.z = acc[i][2] + bs[2]; o0.w = acc[i][3] + bs[3];
    o1.x = acc[i][4] + bs[4]; o1.y = acc[i][5] + bs[5]; o1.z = acc[i][6] + bs[6]; o1.w = acc[i][7] + bs[7];
    *(float4*)&Out[(size_t)row * 128 + p0]     = o0;
    *(float4*)&Out[(size_t)row * 128 + p0 + 4] = o1;
  }
}

// ---------------- KNN pass 1: per-(query,slice) top-16 via sorted insertion ----------------
__global__ __launch_bounds__(256) void k_knn_part(const float* __restrict__ xyzT,
                                                  float* __restrict__ candD,
                                                  int* __restrict__ candI) {
  const int T = blockIdx.x * 256 + threadIdx.x;   // 131072 threads
  const int q = T & (NPTS - 1);
  const int slice = T >> 13;                      // 16 slices of 512 points
  const float qx = xyzT[3 * NPTS + q];
  const float qy = xyzT[4 * NPTS + q];
  const float qz = xyzT[5 * NPTS + q];
  const float* xt = xyzT;
  const float* yt = xyzT + NPTS;
  const float* zt = xyzT + 2 * NPTS;

  float d[16]; int pi[16];
  #pragma unroll
  for (int j = 0; j < 16; ++j) { d[j] = 3.4e38f; pi[j] = 0; }

  const int base = slice * 512;
  for (int jj = 0; jj < 512; ++jj) {
    const int p = base + jj;
    float dx = qx - xt[p], dy = qy - yt[p], dz = qz - zt[p];
    float dd = fmaf(dx, dx, fmaf(dy, dy, dz * dz));
    if (dd < d[15]) {            // strict < : earlier (lower) index wins ties
      #pragma unroll
      for (int s = 15; s >= 1; --s) {
        bool cm1 = dd < d[s - 1];
        bool cs  = dd < d[s];
        d[s]  = cm1 ? d[s - 1]  : (cs ? dd : d[s]);
        pi[s] = cm1 ? pi[s - 1] : (cs ? p  : pi[s]);
      }
      bool c0 = dd < d[0];
      d[0]  = c0 ? dd : d[0];
      pi[0] = c0 ? p  : pi[0];
    }
  }
  #pragma unroll
  for (int j = 0; j < 16; ++j) {
    candD[(size_t)(slice * 16 + j) * NPTS + q] = d[j];
    candI[(size_t)(slice * 16 + j) * NPTS + q] = pi[j];
  }
}

// ---------------- KNN pass 2: merge 16 slices, lex (dist,idx) order ----------------
__global__ __launch_bounds__(256) void k_knn_merge(const float* __restrict__ candD,
                                                   const int* __restrict__ candI,
                                                   int* __restrict__ idxo) {
  const int q = blockIdx.x * 256 + threadIdx.x;   // 8192 threads
  unsigned long long key[16];
  #pragma unroll
  for (int j = 0; j < 16; ++j) key[j] = ~0ull;
  for (int s = 0; s < 256; ++s) {
    float dv = candD[(size_t)s * NPTS + q];
    unsigned int pv = (unsigned int)candI[(size_t)s * NPTS + q];
    unsigned long long kk = ((unsigned long long)__float_as_uint(dv) << 32) | pv;
    if (kk < key[15]) {
      #pragma unroll
      for (int u = 15; u >= 1; --u) {
        bool cm1 = kk < key[u - 1];
        bool cs  = kk < key[u];
        key[u] = cm1 ? key[u - 1] : (cs ? kk : key[u]);
      }
      key[0] = (kk < key[0]) ? kk : key[0];
    }
  }
  #pragma unroll
  for (int j = 0; j < 16; ++j) idxo[q * 16 + j] = (int)(key[j] & 0xffffffffull);
}

// ---------------- stats1: per-channel sum/sumsq of w = Q[n] - Kp[idx] ----------------
__global__ __launch_bounds__(256) void k_stats1(const float* __restrict__ Q,
                                                const float* __restrict__ Kp,
                                                const int* __restrict__ idx,
                                                float* __restrict__ stats1) {
  const int t = threadIdx.x;
  const int o = t & 127, h = t >> 7;
  float s = 0.f, q2 = 0.f;
  const int base = blockIdx.x * 512;
  for (int i = 0; i < 256; ++i) {
    const int row = base + i * 2 + h;
    const int n = row >> 4;
    const int pid = idx[row];
    float w = Q[(size_t)n * 128 + o] - Kp[(size_t)pid * 128 + o];
    s += w; q2 += w * w;
  }
  __shared__ float rs[256], rq[256];
  rs[t] = s; rq[t] = q2;
  __syncthreads();
  if (t < 128) {
    atomicAdd(&stats1[o],       rs[t] + rs[t + 128]);
    atomicAdd(&stats1[128 + o], rq[t] + rq[t + 128]);
  }
}

// ---------------- BN finalize: scale/shift from (sum,sumsq) ----------------
__global__ void k_bnfin(const float* __restrict__ stats, int nrep, float invM,
                        const float* __restrict__ gamma, const float* __restrict__ beta,
                        float* __restrict__ bn) {
  const int o = threadIdx.x;  // 128
  float s = 0.f, q = 0.f;
  for (int r = 0; r < nrep; ++r) { s += stats[r * 256 + o]; q += stats[r * 256 + 128 + o]; }
  float mean = s * invM;
  float var  = fmaf(-mean, mean, q * invM);     // biased variance
  float sc = gamma[o] * rsqrtf(var + BN_EPS);
  bn[o]       = sc;
  bn[128 + o] = fmaf(-mean, sc, beta[o]);
}

// ---------------- mid GEMM: y = leaky(bn1(w)) @ Wl^T + bl ; + BN2 stats; y -> bf16 ----------------
__global__ __launch_bounds__(256) void k_mid(const float* __restrict__ Q,
                                             const float* __restrict__ Kp,
                                             const int* __restrict__ idx,
                                             const float* __restrict__ WTl,
                                             const float* __restrict__ bl,
                                             const float* __restrict__ bn1,
                                             float* __restrict__ stats2,
                                             unsigned short* __restrict__ Y) {
  __shared__ unsigned short aT[128 * 72];
  __shared__ unsigned short wT[128 * 128];
  __shared__ float red[4 * 16 * 16];
  const int t = threadIdx.x;
  const int rowbase = blockIdx.x * 64;
  {
    const int c = t & 127, half = t >> 7;
    const float s1 = bn1[c], sh1 = bn1[128 + c];
    #pragma unroll
    for (int i = 0; i < 16; ++i) {
      const int r = half * 32 + i * 2;
      const int g0 = rowbase + r, g1 = g0 + 1;
      const int n0 = g0 >> 4, n1 = g1 >> 4;
      const int pa = idx[g0], pb = idx[g1];
      float w0 = Q[(size_t)n0 * 128 + c] - Kp[(size_t)pa * 128 + c];
      float w1 = Q[(size_t)n1 * 128 + c] - Kp[(size_t)pb * 128 + c];
      float x0 = fmaf(w0, s1, sh1); x0 = (x0 >= 0.f) ? x0 : SLOPE * x0;
      float x1 = fmaf(w1, s1, sh1); x1 = (x1 >= 0.f) ? x1 : SLOPE * x1;
      *(unsigned int*)&aT[c * 72 + r] = pack_bf2(x0, x1);
    }
    #pragma unroll
    for (int i = 0; i < 32; ++i) {
      const int e = i * 512 + t * 2;
      *(unsigned int*)&wT[e] = pack_bf2(WTl[e], WTl[e + 1]);
    }
  }
  __syncthreads();
  const int cg = t & 15, rg = t >> 4;
  const int p0 = cg * 8, r0 = rg * 4;
  float acc[4][8];
  #pragma unroll
  for (int i = 0; i < 4; ++i)
    #pragma unroll
    for (int j = 0; j < 8; ++j) acc[i][j] = 0.f;

  #pragma unroll 4
  for (int c = 0; c < 128; ++c) {
    uint2 au = *(const uint2*)&aT[c * 72 + r0];
    uint4 bu = *(const uint4*)&wT[c * 128 + p0];
    float a0, a1, a2, a3, b[8];
    unpack2(au.x, a0, a1); unpack2(au.y, a2, a3);
    unpack2(bu.x, b[0], b[1]); unpack2(bu.y, b[2], b[3]);
    unpack2(bu.z, b[4], b[5]); unpack2(bu.w, b[6], b[7]);
    #pragma unroll
    for (int j = 0; j < 8; ++j) {
      acc[0][j] = fmaf(a0, b[j], acc[0][j]);
      acc[1][j] = fmaf(a1, b[j], acc[1][j]);
      acc[2][j] = fmaf(a2, b[j], acc[2][j]);
      acc[3][j] = fmaf(a3, b[j], acc[3][j]);
    }
  }
  float bs[8];
  #pragma unroll
  for (int j = 0; j < 8; ++j) bs[j] = bl[p0 + j];
  float ssum[8], sqq[8];
  #pragma unroll
  for (int j = 0; j < 8; ++j) { ssum[j] = 0.f; sqq[j] = 0.f; }
  #pragma unroll
  for (int i = 0; i < 4; ++i) {
    float zv[8];
    #pragma unroll
    for (int j = 0; j < 8; ++j) { zv[j] = acc[i][j] + bs[j]; ssum[j] += zv[j]; sqq[j] += zv[j] * zv[j]; }
    uint4 st;
    st.x = pack_bf2(zv[0], zv[1]); st.y = pack_bf2(zv[2], zv[3]);
    st.z = pack_bf2(zv[4], zv[5]); st.w = pack_bf2(zv[6], zv[7]);
    *(uint4*)&Y[(size_t)(rowbase + r0 + i) * 128 + p0] = st;
  }
  // reduce stats over the 4 rgrps within each wave (lanes xor 16,32), then across waves via LDS
  #pragma unroll
  for (int j = 0; j < 8; ++j) {
    ssum[j] += __shfl_xor(ssum[j], 16); ssum[j] += __shfl_xor(ssum[j], 32);
    sqq[j]  += __shfl_xor(sqq[j], 16);  sqq[j]  += __shfl_xor(sqq[j], 32);
  }
  const int lane = t & 63, wave = t >> 6;
  if (lane < 16) {
    #pragma unroll
    for (int j = 0; j < 8; ++j) {
      red[(wave * 16 + lane) * 16 + j]     = ssum[j];
      red[(wave * 16 + lane) * 16 + 8 + j] = sqq[j];
    }
  }
  __syncthreads();
  {
    const int cg2 = t >> 4, v = t & 15;
    float tot = red[(0 * 16 + cg2) * 16 + v] + red[(1 * 16 + cg2) * 16 + v]
              + red[(2 * 16 + cg2) * 16 + v] + red[(3 * 16 + cg2) * 16 + v];
    const int p = cg2 * 8 + (v & 7);
    const int stat = v >> 3;
    atomicAdd(&stats2[(blockIdx.x & 15) * 256 + stat * 128 + p], tot);
  }
}

// ---------------- epilogue: BN2+leaky -> softmax over K -> weighted V gather ----------------
__global__ __launch_bounds__(128) void k_epi(const unsigned short* __restrict__ Y,
                                             const float* __restrict__ Vp,
                                             const int* __restrict__ idx,
                                             const float* __restrict__ bn2,
                                             float* __restrict__ out) {
  const int n = blockIdx.x;
  const int p = threadIdx.x;
  const float s2 = bn2[p], sh2 = bn2[128 + p];
  float z[16];
  #pragma unroll
  for (int k = 0; k < 16; ++k) {
    float yv = bf2f(Y[(size_t)(n * 16 + k) * 128 + p]);
    float v = fmaf(yv, s2, sh2);
    z[k] = (v >= 0.f) ? v : SLOPE * v;
  }
  float m = z[0];
  #pragma unroll
  for (int k = 1; k < 16; ++k) m = fmaxf(m, z[k]);
  float acc = 0.f, denom = 0.f;
  #pragma unroll
  for (int k = 0; k < 16; ++k) {
    float e = __expf(z[k] - m);
    denom += e;
    const int pid = idx[n * 16 + k];
    acc = fmaf(e, Vp[(size_t)pid * 128 + p], acc);
  }
  out[(size_t)n * 128 + p] = acc / denom;
}

extern "C" void kernel_launch(void* const* d_in, const int* in_sizes, int n_in,
                              void* d_out, int out_size, void* d_ws, size_t ws_size,
                              hipStream_t stream) {
  const float* fea_i    = (const float*)d_in[0];
  const float* fea_last = (const float*)d_in[1];
  const float* xyz_i    = (const float*)d_in[2];
  const float* xyz_last = (const float*)d_in[3];
  // d_in[4] = batch (single batch, unused)
  const float* Wq = (const float*)d_in[5];
  const float* bq = (const float*)d_in[6];
  const float* Wk = (const float*)d_in[7];
  const float* bk = (const float*)d_in[8];
  const float* Wv = (const float*)d_in[9];
  const float* bv = (const float*)d_in[10];
  const float* g1 = (const float*)d_in[11];
  const float* b1 = (const float*)d_in[12];
  const float* Wl = (const float*)d_in[13];
  const float* bl = (const float*)d_in[14];
  const float* g2 = (const float*)d_in[15];
  const float* b2 = (const float*)d_in[16];

  if (ws_size < (size_t)WS_NEED) return;  // need ~45 MiB scratch

  char* ws = (char*)d_ws;
  float* Q      = (float*)(ws + OFF_Q);
  float* Kp     = (float*)(ws + OFF_KP);
  float* Vp     = (float*)(ws + OFF_VP);
  float* WT     = (float*)(ws + OFF_WT);
  float* xyzT   = (float*)(ws + OFF_XYZT);
  int*   idxb   = (int*)  (ws + OFF_IDX);
  float* stats1 = (float*)(ws + OFF_STATS);
  float* bn1    = stats1 + 256;
  float* stats2 = stats1 + 512;
  float* bn2    = stats1 + 512 + 4096;
  float* candD  = (float*)(ws + OFF_BIG);
  int*   candI  = (int*)  (ws + OFF_BIG + 8388608u);
  unsigned short* Y = (unsigned short*)(ws + OFF_BIG);  // aliases cand buffers (dead by then)

  k_prep<<<64, 256, 0, stream>>>(xyz_i, xyz_last, Wq, Wk, Wv, Wl, xyzT, WT, stats1);
  k_proj<<<dim3(128, 3), 256, 0, stream>>>(fea_i, fea_last, WT, bq, bk, bv, Q, Kp, Vp);
  k_knn_part<<<512, 256, 0, stream>>>(xyzT, candD, candI);
  k_knn_merge<<<32, 256, 0, stream>>>(candD, candI, idxb);
  k_stats1<<<256, 256, 0, stream>>>(Q, Kp, idxb, stats1);
  k_bnfin<<<1, 128, 0, stream>>>(stats1, 1, 1.f / (float)NROWS, g1, b1, bn1);
  k_mid<<<2048, 256, 0, stream>>>(Q, Kp, idxb, WT + 3 * 16384, bl, bn1, stats2, Y);
  k_bnfin<<<1, 128, 0, stream>>>(stats2, 16, 1.f / (float)NROWS, g2, b2, bn2);
  k_epi<<<8192, 128, 0, stream>>>(Y, Vp, idxb, bn2, (float*)d_out);
}

// Round 4
// 624.257 us; speedup vs baseline: 1.0024x; 1.0008x over previous
//
#include <hip/hip_runtime.h>
#include <stdint.h>

#define NPTS   8192
#define NROWS  (NPTS * 16)
#define SLOPE  0.01f
#define BN_EPS 1e-5f

// ---- workspace layout (bytes) ----
#define OFF_Q      0u          // 8192x128 f32  (fea_last @ Wq^T + bq)
#define OFF_KP     4194304u    // 8192x128 f32
#define OFF_VP     8388608u    // 8192x128 f32
#define OFF_WT     12582912u   // 4 x 128x128 f32 transposed: WqT WkT WvT WlT (c-major: WT[c*128+o] = W[o*128+c])
#define OFF_XYZT   12845056u   // 6 x 8192 f32: xi yi zi | xl yl zl
#define OFF_IDX    13041664u   // 131072 i32 (8192 x 16 neighbor ids)
#define OFF_STATS  13565952u   // 4864 f32: stats1[256] bn1[256] stats2[16*256] bn2[256]
#define OFF_BIG    13585408u   // candD(8MB)+candI(8MB), later aliased by Y bf16 (33.5MB)
#define WS_NEED    47139840u

__device__ __forceinline__ unsigned int pack_bf2(float lo, float hi) {
  unsigned int a = __float_as_uint(lo);
  unsigned int b = __float_as_uint(hi);
  unsigned int ra = (a + 0x7fffu + ((a >> 16) & 1u)) >> 16;           // RNE bf16 of lo
  unsigned int rb = (b + 0x7fffu + ((b >> 16) & 1u)) & 0xffff0000u;   // RNE bf16 of hi in high half
  return ra | rb;
}
__device__ __forceinline__ void unpack2(unsigned int u, float& lo, float& hi) {
  lo = __uint_as_float(u << 16);
  hi = __uint_as_float(u & 0xffff0000u);
}
__device__ __forceinline__ float bf2f(unsigned short u) {
  return __uint_as_float(((unsigned int)u) << 16);
}

// ---------------- prep: transpose xyz + weights, zero stats ----------------
__global__ __launch_bounds__(256) void k_prep(const float* __restrict__ xyz_i,
                                              const float* __restrict__ xyz_last,
                                              const float* __restrict__ Wq,
                                              const float* __restrict__ Wk,
                                              const float* __restrict__ Wv,
                                              const float* __restrict__ Wl,
                                              float* __restrict__ xyzT,
                                              float* __restrict__ WT,
                                              float* __restrict__ stats_zero) {
  int t = blockIdx.x * 256 + threadIdx.x;   // 16384 threads
  if (t < NPTS) {
    xyzT[0 * NPTS + t] = xyz_i[t * 3 + 0];
    xyzT[1 * NPTS + t] = xyz_i[t * 3 + 1];
    xyzT[2 * NPTS + t] = xyz_i[t * 3 + 2];
    xyzT[3 * NPTS + t] = xyz_last[t * 3 + 0];
    xyzT[4 * NPTS + t] = xyz_last[t * 3 + 1];
    xyzT[5 * NPTS + t] = xyz_last[t * 3 + 2];
  }
  {
    int o = t >> 7, c = t & 127;
    WT[0 * 16384 + c * 128 + o] = Wq[t];
    WT[1 * 16384 + c * 128 + o] = Wk[t];
    WT[2 * 16384 + c * 128 + o] = Wv[t];
    WT[3 * 16384 + c * 128 + o] = Wl[t];
  }
  if (t < 4864) stats_zero[t] = 0.f;
}

// ---------------- projections: Out = A @ W^T + b (8192x128 @ 128x128) ----------------
// 64 rows/block, 256 threads, per-thread 4x8 tile, bf16 operands in LDS, f32 accum.
__global__ __launch_bounds__(256) void k_proj(const float* __restrict__ fea_i,
                                              const float* __restrict__ fea_last,
                                              const float* __restrict__ WT,
                                              const float* __restrict__ bq,
                                              const float* __restrict__ bk,
                                              const float* __restrict__ bv,
                                              float* __restrict__ Qo,
                                              float* __restrict__ Kpo,
                                              float* __restrict__ Vpo) {
  const int z = blockIdx.y;
  const float* A    = (z == 0) ? fea_last : fea_i;
  const float* WTz  = WT + z * 16384;
  const float* bias = (z == 0) ? bq : ((z == 1) ? bk : bv);
  float* Out        = (z == 0) ? Qo : ((z == 1) ? Kpo : Vpo);

  __shared__ unsigned short aT[128 * 72];    // [c][r], r<64, pad 72
  __shared__ unsigned short wT[128 * 128];   // [c][o] bf16
  const int t = threadIdx.x;
  const int rowbase = blockIdx.x * 64;
  {
    const int c = t & 127, half = t >> 7;
    #pragma unroll
    for (int i = 0; i < 16; ++i) {
      const int r = half * 32 + i * 2;
      float v0 = A[(size_t)(rowbase + r) * 128 + c];
      float v1 = A[(size_t)(rowbase + r + 1) * 128 + c];
      *(unsigned int*)&aT[c * 72 + r] = pack_bf2(v0, v1);
    }
    #pragma unroll
    for (int i = 0; i < 32; ++i) {
      const int e = i * 512 + t * 2;
      *(unsigned int*)&wT[e] = pack_bf2(WTz[e], WTz[e + 1]);
    }
  }
  __syncthreads();
  const int cg = t & 15, rg = t >> 4;
  const int p0 = cg * 8, r0 = rg * 4;
  float acc[4][8];
  #pragma unroll
  for (int i = 0; i < 4; ++i)
    #pragma unroll
    for (int j = 0; j < 8; ++j) acc[i][j] = 0.f;

  #pragma unroll 4
  for (int c = 0; c < 128; ++c) {
    uint2 au = *(const uint2*)&aT[c * 72 + r0];
    uint4 bu = *(const uint4*)&wT[c * 128 + p0];
    float a0, a1, a2, a3, b[8];
    unpack2(au.x, a0, a1); unpack2(au.y, a2, a3);
    unpack2(bu.x, b[0], b[1]); unpack2(bu.y, b[2], b[3]);
    unpack2(bu.z, b[4], b[5]); unpack2(bu.w, b[6], b[7]);
    #pragma unroll
    for (int j = 0; j < 8; ++j) {
      acc[0][j] = fmaf(a0, b[j], acc[0][j]);
      acc[1][j] = fmaf(a1, b[j], acc[1][j]);
      acc[2][j] = fmaf(a2, b[j], acc[2][j]);
      acc[3][j] = fmaf(a3, b[j], acc[3][j]);
    }
  }
  float bs[8];
  #pragma unroll
  for (int j = 0; j < 8; ++j) bs[j] = bias[p0 + j];
  #pragma unroll
  for (int i = 0; i < 4; ++i) {
    const int row = rowbase + r0 + i;
    float4 o0, o1;
    o0.x = acc[i][0] + bs[0]; o0.y = acc[i][1] + bs[1]; o0.z = acc[i][2] + bs[2]; o0.w = acc[i][3] + bs[3];
    o1.x = acc[i][4] + bs[4]; o1.y = acc[i][5] + bs[5]; o1.z = acc[i][6] + bs[6]; o1.w = acc[i][7] + bs[7];
    *(float4*)&Out[(size_t)row * 128 + p0]     = o0;
    *(float4*)&Out[(size_t)row * 128 + p0 + 4] = o1;
  }
}

// ---------------- KNN pass 1: per-(query,slice) top-16 via sorted insertion ----------------
__global__ __launch_bounds__(256) void k_knn_part(const float* __restrict__ xyzT,
                                                  float* __restrict__ candD,
                                                  int* __restrict__ candI) {
  const int T = blockIdx.x * 256 + threadIdx.x;   // 131072 threads
  const int q = T & (NPTS - 1);
  const int slice = T >> 13;                      // 16 slices of 512 points
  const float qx = xyzT[3 * NPTS + q];
  const float qy = xyzT[4 * NPTS + q];
  const float qz = xyzT[5 * NPTS + q];
  const float* xt = xyzT;
  const float* yt = xyzT + NPTS;
  const float* zt = xyzT + 2 * NPTS;

  float d[16]; int pi[16];
  #pragma unroll
  for (int j = 0; j < 16; ++j) { d[j] = 3.4e38f; pi[j] = 0; }

  const int base = slice * 512;
  for (int jj = 0; jj < 512; ++jj) {
    const int p = base + jj;
    float dx = qx - xt[p], dy = qy - yt[p], dz = qz - zt[p];
    float dd = fmaf(dx, dx, fmaf(dy, dy, dz * dz));
    if (dd < d[15]) {            // strict < : earlier (lower) index wins ties
      #pragma unroll
      for (int s = 15; s >= 1; --s) {
        bool cm1 = dd < d[s - 1];
        bool cs  = dd < d[s];
        d[s]  = cm1 ? d[s - 1]  : (cs ? dd : d[s]);
        pi[s] = cm1 ? pi[s - 1] : (cs ? p  : pi[s]);
      }
      bool c0 = dd < d[0];
      d[0]  = c0 ? dd : d[0];
      pi[0] = c0 ? p  : pi[0];
    }
  }
  #pragma unroll
  for (int j = 0; j < 16; ++j) {
    candD[(size_t)(slice * 16 + j) * NPTS + q] = d[j];
    candI[(size_t)(slice * 16 + j) * NPTS + q] = pi[j];
  }
}

// ---------------- KNN pass 2: merge 16 slices, lex (dist,idx) order ----------------
__global__ __launch_bounds__(256) void k_knn_merge(const float* __restrict__ candD,
                                                   const int* __restrict__ candI,
                                                   int* __restrict__ idxo) {
  const int q = blockIdx.x * 256 + threadIdx.x;   // 8192 threads
  unsigned long long key[16];
  #pragma unroll
  for (int j = 0; j < 16; ++j) key[j] = ~0ull;
  for (int s = 0; s < 256; ++s) {
    float dv = candD[(size_t)s * NPTS + q];
    unsigned int pv = (unsigned int)candI[(size_t)s * NPTS + q];
    unsigned long long kk = ((unsigned long long)__float_as_uint(dv) << 32) | pv;
    if (kk < key[15]) {
      #pragma unroll
      for (int u = 15; u >= 1; --u) {
        bool cm1 = kk < key[u - 1];
        bool cs  = kk < key[u];
        key[u] = cm1 ? key[u - 1] : (cs ? kk : key[u]);
      }
      key[0] = (kk < key[0]) ? kk : key[0];
    }
  }
  #pragma unroll
  for (int j = 0; j < 16; ++j) idxo[q * 16 + j] = (int)(key[j] & 0xffffffffull);
}

// ---------------- stats1: per-channel sum/sumsq of w = Q[n] - Kp[idx] ----------------
__global__ __launch_bounds__(256) void k_stats1(const float* __restrict__ Q,
                                                const float* __restrict__ Kp,
                                                const int* __restrict__ idx,
                                                float* __restrict__ stats1) {
  const int t = threadIdx.x;
  const int o = t & 127, h = t >> 7;
  float s = 0.f, q2 = 0.f;
  const int base = blockIdx.x * 512;
  for (int i = 0; i < 256; ++i) {
    const int row = base + i * 2 + h;
    const int n = row >> 4;
    const int pid = idx[row];
    float w = Q[(size_t)n * 128 + o] - Kp[(size_t)pid * 128 + o];
    s += w; q2 += w * w;
  }
  __shared__ float rs[256], rq[256];
  rs[t] = s; rq[t] = q2;
  __syncthreads();
  if (t < 128) {
    atomicAdd(&stats1[o],       rs[t] + rs[t + 128]);
    atomicAdd(&stats1[128 + o], rq[t] + rq[t + 128]);
  }
}

// ---------------- BN finalize: scale/shift from (sum,sumsq) ----------------
__global__ void k_bnfin(const float* __restrict__ stats, int nrep, float invM,
                        const float* __restrict__ gamma, const float* __restrict__ beta,
                        float* __restrict__ bn) {
  const int o = threadIdx.x;  // 128
  float s = 0.f, q = 0.f;
  for (int r = 0; r < nrep; ++r) { s += stats[r * 256 + o]; q += stats[r * 256 + 128 + o]; }
  float mean = s * invM;
  float var  = fmaf(-mean, mean, q * invM);     // biased variance
  float sc = gamma[o] * rsqrtf(var + BN_EPS);
  bn[o]       = sc;
  bn[128 + o] = fmaf(-mean, sc, beta[o]);
}

// ---------------- mid GEMM: y = leaky(bn1(w)) @ Wl^T + bl ; + BN2 stats; y -> bf16 ----------------
__global__ __launch_bounds__(256) void k_mid(const float* __restrict__ Q,
                                             const float* __restrict__ Kp,
                                             const int* __restrict__ idx,
                                             const float* __restrict__ WTl,
                                             const float* __restrict__ bl,
                                             const float* __restrict__ bn1,
                                             float* __restrict__ stats2,
                                             unsigned short* __restrict__ Y) {
  __shared__ unsigned short aT[128 * 72];
  __shared__ unsigned short wT[128 * 128];
  __shared__ float red[4 * 16 * 16];
  const int t = threadIdx.x;
  const int rowbase = blockIdx.x * 64;
  {
    const int c = t & 127, half = t >> 7;
    const float s1 = bn1[c], sh1 = bn1[128 + c];
    #pragma unroll
    for (int i = 0; i < 16; ++i) {
      const int r = half * 32 + i * 2;
      const int g0 = rowbase + r, g1 = g0 + 1;
      const int n0 = g0 >> 4, n1 = g1 >> 4;
      const int pa = idx[g0], pb = idx[g1];
      float w0 = Q[(size_t)n0 * 128 + c] - Kp[(size_t)pa * 128 + c];
      float w1 = Q[(size_t)n1 * 128 + c] - Kp[(size_t)pb * 128 + c];
      float x0 = fmaf(w0, s1, sh1); x0 = (x0 >= 0.f) ? x0 : SLOPE * x0;
      float x1 = fmaf(w1, s1, sh1); x1 = (x1 >= 0.f) ? x1 : SLOPE * x1;
      *(unsigned int*)&aT[c * 72 + r] = pack_bf2(x0, x1);
    }
    #pragma unroll
    for (int i = 0; i < 32; ++i) {
      const int e = i * 512 + t * 2;
      *(unsigned int*)&wT[e] = pack_bf2(WTl[e], WTl[e + 1]);
    }
  }
  __syncthreads();
  const int cg = t & 15, rg = t >> 4;
  const int p0 = cg * 8, r0 = rg * 4;
  float acc[4][8];
  #pragma unroll
  for (int i = 0; i < 4; ++i)
    #pragma unroll
    for (int j = 0; j < 8; ++j) acc[i][j] = 0.f;

  #pragma unroll 4
  for (int c = 0; c < 128; ++c) {
    uint2 au = *(const uint2*)&aT[c * 72 + r0];
    uint4 bu = *(const uint4*)&wT[c * 128 + p0];
    float a0, a1, a2, a3, b[8];
    unpack2(au.x, a0, a1); unpack2(au.y, a2, a3);
    unpack2(bu.x, b[0], b[1]); unpack2(bu.y, b[2], b[3]);
    unpack2(bu.z, b[4], b[5]); unpack2(bu.w, b[6], b[7]);
    #pragma unroll
    for (int j = 0; j < 8; ++j) {
      acc[0][j] = fmaf(a0, b[j], acc[0][j]);
      acc[1][j] = fmaf(a1, b[j], acc[1][j]);
      acc[2][j] = fmaf(a2, b[j], acc[2][j]);
      acc[3][j] = fmaf(a3, b[j], acc[3][j]);
    }
  }
  float bs[8];
  #pragma unroll
  for (int j = 0; j < 8; ++j) bs[j] = bl[p0 + j];
  float ssum[8], sqq[8];
  #pragma unroll
  for (int j = 0; j < 8; ++j) { ssum[j] = 0.f; sqq[j] = 0.f; }
  #pragma unroll
  for (int i = 0; i < 4; ++i) {
    float zv[8];
    #pragma unroll
    for (int j = 0; j < 8; ++j) { zv[j] = acc[i][j] + bs[j]; ssum[j] += zv[j]; sqq[j] += zv[j] * zv[j]; }
    uint4 st;
    st.x = pack_bf2(zv[0], zv[1]); st.y = pack_bf2(zv[2], zv[3]);
    st.z = pack_bf2(zv[4], zv[5]); st.w = pack_bf2(zv[6], zv[7]);
    *(uint4*)&Y[(size_t)(rowbase + r0 + i) * 128 + p0] = st;
  }
  // reduce stats over the 4 rgrps within each wave (lanes xor 16,32), then across waves via LDS
  #pragma unroll
  for (int j = 0; j < 8; ++j) {
    ssum[j] += __shfl_xor(ssum[j], 16); ssum[j] += __shfl_xor(ssum[j], 32);
    sqq[j]  += __shfl_xor(sqq[j], 16);  sqq[j]  += __shfl_xor(sqq[j], 32);
  }
  const int lane = t & 63, wave = t >> 6;
  if (lane < 16) {
    #pragma unroll
    for (int j = 0; j < 8; ++j) {
      red[(wave * 16 + lane) * 16 + j]     = ssum[j];
      red[(wave * 16 + lane) * 16 + 8 + j] = sqq[j];
    }
  }
  __syncthreads();
  {
    const int cg2 = t >> 4, v = t & 15;
    float tot = red[(0 * 16 + cg2) * 16 + v] + red[(1 * 16 + cg2) * 16 + v]
              + red[(2 * 16 + cg2) * 16 + v] + red[(3 * 16 + cg2) * 16 + v];
    const int p = cg2 * 8 + (v & 7);
    const int stat = v >> 3;
    atomicAdd(&stats2[(blockIdx.x & 15) * 256 + stat * 128 + p], tot);
  }
}

// ---------------- epilogue: BN2+leaky -> softmax over K -> weighted V gather ----------------
__global__ __launch_bounds__(128) void k_epi(const unsigned short* __restrict__ Y,
                                             const float* __restrict__ Vp,
                                             const int* __restrict__ idx,
                                             const float* __restrict__ bn2,
                                             float* __restrict__ out) {
  const int n = blockIdx.x;
  const int p = threadIdx.x;
  const float s2 = bn2[p], sh2 = bn2[128 + p];
  float z[16];
  #pragma unroll
  for (int k = 0; k < 16; ++k) {
    float yv = bf2f(Y[(size_t)(n * 16 + k) * 128 + p]);
    float v = fmaf(yv, s2, sh2);
    z[k] = (v >= 0.f) ? v : SLOPE * v;
  }
  float m = z[0];
  #pragma unroll
  for (int k = 1; k < 16; ++k) m = fmaxf(m, z[k]);
  float acc = 0.f, denom = 0.f;
  #pragma unroll
  for (int k = 0; k < 16; ++k) {
    float e = __expf(z[k] - m);
    denom += e;
    const int pid = idx[n * 16 + k];
    acc = fmaf(e, Vp[(size_t)pid * 128 + p], acc);
  }
  out[(size_t)n * 128 + p] = acc / denom;
}

extern "C" void kernel_launch(void* const* d_in, const int* in_sizes, int n_in,
                              void* d_out, int out_size, void* d_ws, size_t ws_size,
                              hipStream_t stream) {
  const float* fea_i    = (const float*)d_in[0];
  const float* fea_last = (const float*)d_in[1];
  const float* xyz_i    = (const float*)d_in[2];
  const float* xyz_last = (const float*)d_in[3];
  // d_in[4] = batch (single batch, unused)
  const float* Wq = (const float*)d_in[5];
  const float* bq = (const float*)d_in[6];
  const float* Wk = (const float*)d_in[7];
  const float* bk = (const float*)d_in[8];
  const float* Wv = (const float*)d_in[9];
  const float* bv = (const float*)d_in[10];
  const float* g1 = (const float*)d_in[11];
  const float* b1 = (const float*)d_in[12];
  const float* Wl = (const float*)d_in[13];
  const float* bl = (const float*)d_in[14];
  const float* g2 = (const float*)d_in[15];
  const float* b2 = (const float*)d_in[16];

  if (ws_size < (size_t)WS_NEED) return;  // need ~45 MiB scratch

  char* ws = (char*)d_ws;
  float* Q      = (float*)(ws + OFF_Q);
  float* Kp     = (float*)(ws + OFF_KP);
  float* Vp     = (float*)(ws + OFF_VP);
  float* WT     = (float*)(ws + OFF_WT);
  float* xyzT   = (float*)(ws + OFF_XYZT);
  int*   idxb   = (int*)  (ws + OFF_IDX);
  float* stats1 = (float*)(ws + OFF_STATS);
  float* bn1    = stats1 + 256;
  float* stats2 = stats1 + 512;
  float* bn2    = stats1 + 512 + 4096;
  float* candD  = (float*)(ws + OFF_BIG);
  int*   candI  = (int*)  (ws + OFF_BIG + 8388608u);
  unsigned short* Y = (unsigned short*)(ws + OFF_BIG);  // aliases cand buffers (dead by then)

  k_prep<<<64, 256, 0, stream>>>(xyz_i, xyz_last, Wq, Wk, Wv, Wl, xyzT, WT, stats1);
  k_proj<<<dim3(128, 3), 256, 0, stream>>>(fea_i, fea_last, WT, bq, bk, bv, Q, Kp, Vp);
  k_knn_part<<<512, 256, 0, stream>>>(xyzT, candD, candI);
  k_knn_merge<<<32, 256, 0, stream>>>(candD, candI, idxb);
  k_stats1<<<256, 256, 0, stream>>>(Q, Kp, idxb, stats1);
  k_bnfin<<<1, 128, 0, stream>>>(stats1, 1, 1.f / (float)NROWS, g1, b1, bn1);
  k_mid<<<2048, 256, 0, stream>>>(Q, Kp, idxb, WT + 3 * 16384, bl, bn1, stats2, Y);
  k_bnfin<<<1, 128, 0, stream>>>(stats2, 16, 1.f / (float)NROWS, g2, b2, bn2);
  k_epi<<<8192, 128, 0, stream>>>(Y, Vp, idxb, bn2, (float*)d_out);
}

// Round 5
// 326.489 us; speedup vs baseline: 1.9165x; 1.9120x over previous
//
#include <hip/hip_runtime.h>
#include <stdint.h>

#define NPTS   8192
#define NROWS  (NPTS * 16)
#define SLOPE  0.01f
#define BN_EPS 1e-5f

// KNN candidate-generation parameters
#define KNN_T2     0.04f   // gate threshold T=0.2 (d16 ~ 0.078 for uniform data)
#define NSLICE     32
#define SLICE_PTS  256
#define SLICE_CAP  30      // per-(q,slice) candidate capacity; overflow -> exact fallback

// ---- workspace layout (bytes) ----
#define OFF_Q      0u          // 8192x128 f32  (fea_last @ Wq^T + bq)
#define OFF_KP     4194304u    // 8192x128 f32
#define OFF_VP     8388608u    // 8192x128 f32
#define OFF_WT     12582912u   // 4 x 128x128 f32 transposed
#define OFF_XYZT   12845056u   // 6 x 8192 f32: xi yi zi | xl yl zl
#define OFF_IDX    13041664u   // 131072 i32 (8192 x 16 neighbor ids)
#define OFF_STATS  13565952u   // 4864 f32: stats1[256] bn1[256] stats2[16*256] bn2[256]
#define OFF_BIG    13585408u   // knn cand buffers, later aliased by Y bf16 (33.5MB)
#define OFF_CIDX   OFF_BIG                  // 32*30 rows x 8192 i32 = 31457280 B
#define OFF_SCNT   (OFF_BIG + 31457280u)    // 32 x 8192 i32 = 1 MB
#define OFF_XYZP   (OFF_BIG + 32505856u)    // 8192 float4 = 131072 B (ends 32636928 <= 33.5MB)
#define WS_NEED    47139840u

__device__ __forceinline__ unsigned int pack_bf2(float lo, float hi) {
  unsigned int a = __float_as_uint(lo);
  unsigned int b = __float_as_uint(hi);
  unsigned int ra = (a + 0x7fffu + ((a >> 16) & 1u)) >> 16;           // RNE bf16 of lo
  unsigned int rb = (b + 0x7fffu + ((b >> 16) & 1u)) & 0xffff0000u;   // RNE bf16 of hi in high half
  return ra | rb;
}
__device__ __forceinline__ void unpack2(unsigned int u, float& lo, float& hi) {
  lo = __uint_as_float(u << 16);
  hi = __uint_as_float(u & 0xffff0000u);
}
__device__ __forceinline__ float bf2f(unsigned short u) {
  return __uint_as_float(((unsigned int)u) << 16);
}

__device__ __forceinline__ void insert16(unsigned long long* key, unsigned long long kk) {
  if (kk < key[15]) {
    #pragma unroll
    for (int u = 15; u >= 1; --u) {
      bool cm1 = kk < key[u - 1];
      bool cs  = kk < key[u];
      key[u] = cm1 ? key[u - 1] : (cs ? kk : key[u]);
    }
    key[0] = (kk < key[0]) ? kk : key[0];
  }
}

// ---------------- prep: transpose xyz + weights, build (x,y,z,|p|^2), zero stats ----------------
__global__ __launch_bounds__(256) void k_prep(const float* __restrict__ xyz_i,
                                              const float* __restrict__ xyz_last,
                                              const float* __restrict__ Wq,
                                              const float* __restrict__ Wk,
                                              const float* __restrict__ Wv,
                                              const float* __restrict__ Wl,
                                              float* __restrict__ xyzT,
                                              float4* __restrict__ xyzp,
                                              float* __restrict__ WT,
                                              float* __restrict__ stats_zero) {
  int t = blockIdx.x * 256 + threadIdx.x;   // 16384 threads
  if (t < NPTS) {
    float x = xyz_i[t * 3 + 0], y = xyz_i[t * 3 + 1], z = xyz_i[t * 3 + 2];
    xyzT[0 * NPTS + t] = x;
    xyzT[1 * NPTS + t] = y;
    xyzT[2 * NPTS + t] = z;
    xyzp[t] = make_float4(x, y, z, fmaf(x, x, fmaf(y, y, z * z)));
    xyzT[3 * NPTS + t] = xyz_last[t * 3 + 0];
    xyzT[4 * NPTS + t] = xyz_last[t * 3 + 1];
    xyzT[5 * NPTS + t] = xyz_last[t * 3 + 2];
  }
  {
    int o = t >> 7, c = t & 127;
    WT[0 * 16384 + c * 128 + o] = Wq[t];
    WT[1 * 16384 + c * 128 + o] = Wk[t];
    WT[2 * 16384 + c * 128 + o] = Wv[t];
    WT[3 * 16384 + c * 128 + o] = Wl[t];
  }
  if (t < 4864) stats_zero[t] = 0.f;
}

// ---------------- projections: Out = A @ W^T + b (8192x128 @ 128x128) ----------------
__global__ __launch_bounds__(256) void k_proj(const float* __restrict__ fea_i,
                                              const float* __restrict__ fea_last,
                                              const float* __restrict__ WT,
                                              const float* __restrict__ bq,
                                              const float* __restrict__ bk,
                                              const float* __restrict__ bv,
                                              float* __restrict__ Qo,
                                              float* __restrict__ Kpo,
                                              float* __restrict__ Vpo) {
  const int z = blockIdx.y;
  const float* A    = (z == 0) ? fea_last : fea_i;
  const float* WTz  = WT + z * 16384;
  const float* bias = (z == 0) ? bq : ((z == 1) ? bk : bv);
  float* Out        = (z == 0) ? Qo : ((z == 1) ? Kpo : Vpo);

  __shared__ unsigned short aT[128 * 72];    // [c][r], r<64, pad 72
  __shared__ unsigned short wT[128 * 128];   // [c][o] bf16
  const int t = threadIdx.x;
  const int rowbase = blockIdx.x * 64;
  {
    const int c = t & 127, half = t >> 7;
    #pragma unroll
    for (int i = 0; i < 16; ++i) {
      const int r = half * 32 + i * 2;
      float v0 = A[(size_t)(rowbase + r) * 128 + c];
      float v1 = A[(size_t)(rowbase + r + 1) * 128 + c];
      *(unsigned int*)&aT[c * 72 + r] = pack_bf2(v0, v1);
    }
    #pragma unroll
    for (int i = 0; i < 32; ++i) {
      const int e = i * 512 + t * 2;
      *(unsigned int*)&wT[e] = pack_bf2(WTz[e], WTz[e + 1]);
    }
  }
  __syncthreads();
  const int cg = t & 15, rg = t >> 4;
  const int p0 = cg * 8, r0 = rg * 4;
  float acc[4][8];
  #pragma unroll
  for (int i = 0; i < 4; ++i)
    #pragma unroll
    for (int j = 0; j < 8; ++j) acc[i][j] = 0.f;

  #pragma unroll 4
  for (int c = 0; c < 128; ++c) {
    uint2 au = *(const uint2*)&aT[c * 72 + r0];
    uint4 bu = *(const uint4*)&wT[c * 128 + p0];
    float a0, a1, a2, a3, b[8];
    unpack2(au.x, a0, a1); unpack2(au.y, a2, a3);
    unpack2(bu.x, b[0], b[1]); unpack2(bu.y, b[2], b[3]);
    unpack2(bu.z, b[4], b[5]); unpack2(bu.w, b[6], b[7]);
    #pragma unroll
    for (int j = 0; j < 8; ++j) {
      acc[0][j] = fmaf(a0, b[j], acc[0][j]);
      acc[1][j] = fmaf(a1, b[j], acc[1][j]);
      acc[2][j] = fmaf(a2, b[j], acc[2][j]);
      acc[3][j] = fmaf(a3, b[j], acc[3][j]);
    }
  }
  float bs[8];
  #pragma unroll
  for (int j = 0; j < 8; ++j) bs[j] = bias[p0 + j];
  #pragma unroll
  for (int i = 0; i < 4; ++i) {
    const int row = rowbase + r0 + i;
    float4 o0, o1;
    o0.x = acc[i][0] + bs[0]; o0.y = acc[i][1] + bs[1]; o0.z = acc[i][2] + bs[2]; o0.w = acc[i][3] + bs[3];
    o1.x = acc[i][4] + bs[4]; o1.y = acc[i][5] + bs[5]; o1.z = acc[i][6] + bs[6]; o1.w = acc[i][7] + bs[7];
    *(float4*)&Out[(size_t)row * 128 + p0]     = o0;
    *(float4*)&Out[(size_t)row * 128 + p0 + 4] = o1;
  }
}

// ---------------- KNN pass 1: gate by threshold, append candidate indices ----------------
// thread (q, slice): scans 256 points of its slice, appends p with d2(q,p) < T2 to a
// private list (no atomics -> deterministic, store is fire-and-forget).
__global__ __launch_bounds__(256) void k_knn_cand(const float* __restrict__ xyzT,
                                                  const float4* __restrict__ xyzp,
                                                  int* __restrict__ scnt,
                                                  int* __restrict__ cidx) {
  const int q = blockIdx.x * 256 + threadIdx.x;   // 8192 queries
  const int slice = blockIdx.y;                   // 32 slices
  const float qx = xyzT[3 * NPTS + q];
  const float qy = xyzT[4 * NPTS + q];
  const float qz = xyzT[5 * NPTS + q];
  const float m2x = -2.f * qx, m2y = -2.f * qy, m2z = -2.f * qz;
  const float thr = KNN_T2 - fmaf(qx, qx, fmaf(qy, qy, qz * qz));
  const int pbase = slice * SLICE_PTS;
  int* mycol = cidx + (size_t)(slice * SLICE_CAP) * NPTS + q;   // column q, rows += NPTS
  int c = 0;
  #pragma unroll 4
  for (int jj = 0; jj < SLICE_PTS; ++jj) {
    const float4 pp = xyzp[pbase + jj];   // wave-uniform address -> scalar load
    // gate-dd = |p|^2 - 2 q.p  (true d2 minus |q|^2, folded into thr)
    float ddp = fmaf(pp.x, m2x, fmaf(pp.y, m2y, fmaf(pp.z, m2z, pp.w)));
    if (ddp < thr) {
      if (c < SLICE_CAP) mycol[(size_t)c * NPTS] = pbase + jj;
      ++c;                                  // c > CAP signals overflow -> fallback
    }
  }
  scnt[slice * NPTS + q] = c;
}

// ---------------- KNN pass 2: exact top-16 among candidates (4 threads/query) ----------------
__global__ __launch_bounds__(256) void k_knn_sel(const float* __restrict__ xyzT,
                                                 const float4* __restrict__ xyzp,
                                                 const int* __restrict__ scnt,
                                                 const int* __restrict__ cidx,
                                                 int* __restrict__ idxo) {
  __shared__ unsigned long long part[256][17];   // padded: byte stride 136 -> no bank conflict
  const int t = threadIdx.x;
  const int lq = t >> 2, sub = t & 3;
  const int q = blockIdx.x * 64 + lq;
  const float qx = xyzT[3 * NPTS + q];
  const float qy = xyzT[4 * NPTS + q];
  const float qz = xyzT[5 * NPTS + q];

  // load my 8 slice counts, validate globally across the 4 subs (quad shuffles)
  int cs[8]; int tot = 0; int over = 0;
  #pragma unroll
  for (int k = 0; k < 8; ++k) {
    const int s = sub * 8 + k;
    cs[k] = scnt[s * NPTS + q];
    tot += cs[k];
    over |= (cs[k] > SLICE_CAP) ? 1 : 0;
  }
  tot += __shfl_xor(tot, 1);  tot += __shfl_xor(tot, 2);
  over += __shfl_xor(over, 1); over += __shfl_xor(over, 2);
  const bool ok = (over == 0) && (tot >= 16);

  unsigned long long key[16];
  #pragma unroll
  for (int j = 0; j < 16; ++j) key[j] = ~0ull;

  if (ok) {
    #pragma unroll
    for (int k = 0; k < 8; ++k) {
      const int s = sub * 8 + k;
      const int* col = cidx + (size_t)(s * SLICE_CAP) * NPTS + q;
      for (int c = 0; c < cs[k]; ++c) {
        const int p = col[(size_t)c * NPTS];
        const float4 pp = xyzp[p];
        float dx = qx - pp.x, dy = qy - pp.y, dz = qz - pp.z;
        float dd = fmaf(dx, dx, fmaf(dy, dy, dz * dz));   // exact same formula as reference path
        insert16(key, ((unsigned long long)__float_as_uint(dd) << 32) | (unsigned int)p);
      }
    }
  } else {
    // exact fallback: full scan (expected never for uniform data)
    for (int p = sub; p < NPTS; p += 4) {
      const float4 pp = xyzp[p];
      float dx = qx - pp.x, dy = qy - pp.y, dz = qz - pp.z;
      float dd = fmaf(dx, dx, fmaf(dy, dy, dz * dz));
      insert16(key, ((unsigned long long)__float_as_uint(dd) << 32) | (unsigned int)p);
    }
  }

  #pragma unroll
  for (int j = 0; j < 16; ++j) part[t][j] = key[j];
  __syncthreads();
  if (sub == 0) {
    #pragma unroll
    for (int s2 = 1; s2 < 4; ++s2) {
      #pragma unroll 1
      for (int j = 0; j < 16; ++j) {
        unsigned long long kk = part[t + s2][j];
        if (kk >= key[15]) break;            // partials sorted ascending -> early out
        insert16(key, kk);
      }
    }
    #pragma unroll
    for (int j = 0; j < 16; ++j) idxo[q * 16 + j] = (int)(key[j] & 0xffffffffull);
  }
}

// ---------------- stats1: per-channel sum/sumsq of w = Q[n] - Kp[idx] ----------------
__global__ __launch_bounds__(256) void k_stats1(const float* __restrict__ Q,
                                                const float* __restrict__ Kp,
                                                const int* __restrict__ idx,
                                                float* __restrict__ stats1) {
  const int t = threadIdx.x;
  const int o = t & 127, h = t >> 7;
  float s = 0.f, q2 = 0.f;
  const int base = blockIdx.x * 512;
  for (int i = 0; i < 256; ++i) {
    const int row = base + i * 2 + h;
    const int n = row >> 4;
    const int pid = idx[row];
    float w = Q[(size_t)n * 128 + o] - Kp[(size_t)pid * 128 + o];
    s += w; q2 += w * w;
  }
  __shared__ float rs[256], rq[256];
  rs[t] = s; rq[t] = q2;
  __syncthreads();
  if (t < 128) {
    atomicAdd(&stats1[o],       rs[t] + rs[t + 128]);
    atomicAdd(&stats1[128 + o], rq[t] + rq[t + 128]);
  }
}

// ---------------- BN finalize: scale/shift from (sum,sumsq) ----------------
__global__ void k_bnfin(const float* __restrict__ stats, int nrep, float invM,
                        const float* __restrict__ gamma, const float* __restrict__ beta,
                        float* __restrict__ bn) {
  const int o = threadIdx.x;  // 128
  float s = 0.f, q = 0.f;
  for (int r = 0; r < nrep; ++r) { s += stats[r * 256 + o]; q += stats[r * 256 + 128 + o]; }
  float mean = s * invM;
  float var  = fmaf(-mean, mean, q * invM);     // biased variance
  float sc = gamma[o] * rsqrtf(var + BN_EPS);
  bn[o]       = sc;
  bn[128 + o] = fmaf(-mean, sc, beta[o]);
}

// ---------------- mid GEMM: y = leaky(bn1(w)) @ Wl^T + bl ; + BN2 stats; y -> bf16 ----------------
__global__ __launch_bounds__(256) void k_mid(const float* __restrict__ Q,
                                             const float* __restrict__ Kp,
                                             const int* __restrict__ idx,
                                             const float* __restrict__ WTl,
                                             const float* __restrict__ bl,
                                             const float* __restrict__ bn1,
                                             float* __restrict__ stats2,
                                             unsigned short* __restrict__ Y) {
  __shared__ unsigned short aT[128 * 72];
  __shared__ unsigned short wT[128 * 128];
  __shared__ float red[4 * 16 * 16];
  const int t = threadIdx.x;
  const int rowbase = blockIdx.x * 64;
  {
    const int c = t & 127, half = t >> 7;
    const float s1 = bn1[c], sh1 = bn1[128 + c];
    #pragma unroll
    for (int i = 0; i < 16; ++i) {
      const int r = half * 32 + i * 2;
      const int g0 = rowbase + r, g1 = g0 + 1;
      const int n0 = g0 >> 4, n1 = g1 >> 4;
      const int pa = idx[g0], pb = idx[g1];
      float w0 = Q[(size_t)n0 * 128 + c] - Kp[(size_t)pa * 128 + c];
      float w1 = Q[(size_t)n1 * 128 + c] - Kp[(size_t)pb * 128 + c];
      float x0 = fmaf(w0, s1, sh1); x0 = (x0 >= 0.f) ? x0 : SLOPE * x0;
      float x1 = fmaf(w1, s1, sh1); x1 = (x1 >= 0.f) ? x1 : SLOPE * x1;
      *(unsigned int*)&aT[c * 72 + r] = pack_bf2(x0, x1);
    }
    #pragma unroll
    for (int i = 0; i < 32; ++i) {
      const int e = i * 512 + t * 2;
      *(unsigned int*)&wT[e] = pack_bf2(WTl[e], WTl[e + 1]);
    }
  }
  __syncthreads();
  const int cg = t & 15, rg = t >> 4;
  const int p0 = cg * 8, r0 = rg * 4;
  float acc[4][8];
  #pragma unroll
  for (int i = 0; i < 4; ++i)
    #pragma unroll
    for (int j = 0; j < 8; ++j) acc[i][j] = 0.f;

  #pragma unroll 4
  for (int c = 0; c < 128; ++c) {
    uint2 au = *(const uint2*)&aT[c * 72 + r0];
    uint4 bu = *(const uint4*)&wT[c * 128 + p0];
    float a0, a1, a2, a3, b[8];
    unpack2(au.x, a0, a1); unpack2(au.y, a2, a3);
    unpack2(bu.x, b[0], b[1]); unpack2(bu.y, b[2], b[3]);
    unpack2(bu.z, b[4], b[5]); unpack2(bu.w, b[6], b[7]);
    #pragma unroll
    for (int j = 0; j < 8; ++j) {
      acc[0][j] = fmaf(a0, b[j], acc[0][j]);
      acc[1][j] = fmaf(a1, b[j], acc[1][j]);
      acc[2][j] = fmaf(a2, b[j], acc[2][j]);
      acc[3][j] = fmaf(a3, b[j], acc[3][j]);
    }
  }
  float bs[8];
  #pragma unroll
  for (int j = 0; j < 8; ++j) bs[j] = bl[p0 + j];
  float ssum[8], sqq[8];
  #pragma unroll
  for (int j = 0; j < 8; ++j) { ssum[j] = 0.f; sqq[j] = 0.f; }
  #pragma unroll
  for (int i = 0; i < 4; ++i) {
    float zv[8];
    #pragma unroll
    for (int j = 0; j < 8; ++j) { zv[j] = acc[i][j] + bs[j]; ssum[j] += zv[j]; sqq[j] += zv[j] * zv[j]; }
    uint4 st;
    st.x = pack_bf2(zv[0], zv[1]); st.y = pack_bf2(zv[2], zv[3]);
    st.z = pack_bf2(zv[4], zv[5]); st.w = pack_bf2(zv[6], zv[7]);
    *(uint4*)&Y[(size_t)(rowbase + r0 + i) * 128 + p0] = st;
  }
  #pragma unroll
  for (int j = 0; j < 8; ++j) {
    ssum[j] += __shfl_xor(ssum[j], 16); ssum[j] += __shfl_xor(ssum[j], 32);
    sqq[j]  += __shfl_xor(sqq[j], 16);  sqq[j]  += __shfl_xor(sqq[j], 32);
  }
  const int lane = t & 63, wave = t >> 6;
  if (lane < 16) {
    #pragma unroll
    for (int j = 0; j < 8; ++j) {
      red[(wave * 16 + lane) * 16 + j]     = ssum[j];
      red[(wave * 16 + lane) * 16 + 8 + j] = sqq[j];
    }
  }
  __syncthreads();
  {
    const int cg2 = t >> 4, v = t & 15;
    float tot = red[(0 * 16 + cg2) * 16 + v] + red[(1 * 16 + cg2) * 16 + v]
              + red[(2 * 16 + cg2) * 16 + v] + red[(3 * 16 + cg2) * 16 + v];
    const int p = cg2 * 8 + (v & 7);
    const int stat = v >> 3;
    atomicAdd(&stats2[(blockIdx.x & 15) * 256 + stat * 128 + p], tot);
  }
}

// ---------------- epilogue: BN2+leaky -> softmax over K -> weighted V gather ----------------
__global__ __launch_bounds__(128) void k_epi(const unsigned short* __restrict__ Y,
                                             const float* __restrict__ Vp,
                                             const int* __restrict__ idx,
                                             const float* __restrict__ bn2,
                                             float* __restrict__ out) {
  const int n = blockIdx.x;
  const int p = threadIdx.x;
  const float s2 = bn2[p], sh2 = bn2[128 + p];
  float z[16];
  #pragma unroll
  for (int k = 0; k < 16; ++k) {
    float yv = bf2f(Y[(size_t)(n * 16 + k) * 128 + p]);
    float v = fmaf(yv, s2, sh2);
    z[k] = (v >= 0.f) ? v : SLOPE * v;
  }
  float m = z[0];
  #pragma unroll
  for (int k = 1; k < 16; ++k) m = fmaxf(m, z[k]);
  float acc = 0.f, denom = 0.f;
  #pragma unroll
  for (int k = 0; k < 16; ++k) {
    float e = __expf(z[k] - m);
    denom += e;
    const int pid = idx[n * 16 + k];
    acc = fmaf(e, Vp[(size_t)pid * 128 + p], acc);
  }
  out[(size_t)n * 128 + p] = acc / denom;
}

extern "C" void kernel_launch(void* const* d_in, const int* in_sizes, int n_in,
                              void* d_out, int out_size, void* d_ws, size_t ws_size,
                              hipStream_t stream) {
  const float* fea_i    = (const float*)d_in[0];
  const float* fea_last = (const float*)d_in[1];
  const float* xyz_i    = (const float*)d_in[2];
  const float* xyz_last = (const float*)d_in[3];
  // d_in[4] = batch (single batch, unused)
  const float* Wq = (const float*)d_in[5];
  const float* bq = (const float*)d_in[6];
  const float* Wk = (const float*)d_in[7];
  const float* bk = (const float*)d_in[8];
  const float* Wv = (const float*)d_in[9];
  const float* bv = (const float*)d_in[10];
  const float* g1 = (const float*)d_in[11];
  const float* b1 = (const float*)d_in[12];
  const float* Wl = (const float*)d_in[13];
  const float* bl = (const float*)d_in[14];
  const float* g2 = (const float*)d_in[15];
  const float* b2 = (const float*)d_in[16];

  if (ws_size < (size_t)WS_NEED) return;

  char* ws = (char*)d_ws;
  float*  Q      = (float*)(ws + OFF_Q);
  float*  Kp     = (float*)(ws + OFF_KP);
  float*  Vp     = (float*)(ws + OFF_VP);
  float*  WT     = (float*)(ws + OFF_WT);
  float*  xyzT   = (float*)(ws + OFF_XYZT);
  int*    idxb   = (int*)  (ws + OFF_IDX);
  float*  stats1 = (float*)(ws + OFF_STATS);
  float*  bn1    = stats1 + 256;
  float*  stats2 = stats1 + 512;
  float*  bn2    = stats1 + 512 + 4096;
  int*    cidx   = (int*)   (ws + OFF_CIDX);
  int*    scnt   = (int*)   (ws + OFF_SCNT);
  float4* xyzp   = (float4*)(ws + OFF_XYZP);
  unsigned short* Y = (unsigned short*)(ws + OFF_BIG);  // aliases knn cand buffers (dead by then)

  k_prep<<<64, 256, 0, stream>>>(xyz_i, xyz_last, Wq, Wk, Wv, Wl, xyzT, xyzp, WT, stats1);
  k_proj<<<dim3(128, 3), 256, 0, stream>>>(fea_i, fea_last, WT, bq, bk, bv, Q, Kp, Vp);
  k_knn_cand<<<dim3(32, NSLICE), 256, 0, stream>>>(xyzT, xyzp, scnt, cidx);
  k_knn_sel<<<128, 256, 0, stream>>>(xyzT, xyzp, scnt, cidx, idxb);
  k_stats1<<<256, 256, 0, stream>>>(Q, Kp, idxb, stats1);
  k_bnfin<<<1, 128, 0, stream>>>(stats1, 1, 1.f / (float)NROWS, g1, b1, bn1);
  k_mid<<<2048, 256, 0, stream>>>(Q, Kp, idxb, WT + 3 * 16384, bl, bn1, stats2, Y);
  k_bnfin<<<1, 128, 0, stream>>>(stats2, 16, 1.f / (float)NROWS, g2, b2, bn2);
  k_epi<<<8192, 128, 0, stream>>>(Y, Vp, idxb, bn2, (float*)d_out);
}

// Round 6
// 263.207 us; speedup vs baseline: 2.3773x; 1.2404x over previous
//
#include <hip/hip_runtime.h>
#include <stdint.h>

#define NPTS   8192
#define NROWS  (NPTS * 16)
#define SLOPE  0.01f
#define BN_EPS 1e-5f

// fused KNN parameters
#define KNN_T2 0.04f   // gate radius T=0.2 ; d16 <= 0.155 even at cube corner (8x margin in volume)
#define CAPQ   416     // per-query candidate pool cap (lambda<=275, +8.6 sigma)
#define QPB    16      // queries per block
#define QPW    4       // queries per wave

// ---- workspace layout (bytes) ----
#define OFF_Q      0u          // 8192x128 f32  (fea_last @ Wq^T + bq)
#define OFF_KP     4194304u    // 8192x128 f32
#define OFF_VP     8388608u    // 8192x128 f32
#define OFF_WT     12582912u   // 4 x 128x128 f32 transposed
#define OFF_XYZT   12845056u   // 6 x 8192 f32: xi yi zi | xl yl zl
#define OFF_IDX    13041664u   // 131072 i32 (8192 x 16 neighbor ids)
#define OFF_STATS  13565952u   // 4864 f32: stats1[256] bn1[256] stats2[16*256] bn2[256]
#define OFF_BIG    13585408u   // xyzp (128KB, dead after knn), later aliased by Y bf16 (33.5MB)
#define WS_NEED    47139840u

__device__ __forceinline__ unsigned int pack_bf2(float lo, float hi) {
  unsigned int a = __float_as_uint(lo);
  unsigned int b = __float_as_uint(hi);
  unsigned int ra = (a + 0x7fffu + ((a >> 16) & 1u)) >> 16;           // RNE bf16 of lo
  unsigned int rb = (b + 0x7fffu + ((b >> 16) & 1u)) & 0xffff0000u;   // RNE bf16 of hi in high half
  return ra | rb;
}
__device__ __forceinline__ void unpack2(unsigned int u, float& lo, float& hi) {
  lo = __uint_as_float(u << 16);
  hi = __uint_as_float(u & 0xffff0000u);
}
__device__ __forceinline__ float bf2f(unsigned short u) {
  return __uint_as_float(((unsigned int)u) << 16);
}

__device__ __forceinline__ void insert16(unsigned long long* key, unsigned long long kk) {
  if (kk < key[15]) {
    #pragma unroll
    for (int u = 15; u >= 1; --u) {
      bool cm1 = kk < key[u - 1];
      bool cs  = kk < key[u];
      key[u] = cm1 ? key[u - 1] : (cs ? kk : key[u]);
    }
    key[0] = (kk < key[0]) ? kk : key[0];
  }
}

// ---------------- prep: transpose xyz + weights, build (x,y,z,|p|^2), zero stats ----------------
__global__ __launch_bounds__(256) void k_prep(const float* __restrict__ xyz_i,
                                              const float* __restrict__ xyz_last,
                                              const float* __restrict__ Wq,
                                              const float* __restrict__ Wk,
                                              const float* __restrict__ Wv,
                                              const float* __restrict__ Wl,
                                              float* __restrict__ xyzT,
                                              float4* __restrict__ xyzp,
                                              float* __restrict__ WT,
                                              float* __restrict__ stats_zero) {
  int t = blockIdx.x * 256 + threadIdx.x;   // 16384 threads
  if (t < NPTS) {
    float x = xyz_i[t * 3 + 0], y = xyz_i[t * 3 + 1], z = xyz_i[t * 3 + 2];
    xyzT[0 * NPTS + t] = x;
    xyzT[1 * NPTS + t] = y;
    xyzT[2 * NPTS + t] = z;
    xyzp[t] = make_float4(x, y, z, fmaf(x, x, fmaf(y, y, z * z)));
    xyzT[3 * NPTS + t] = xyz_last[t * 3 + 0];
    xyzT[4 * NPTS + t] = xyz_last[t * 3 + 1];
    xyzT[5 * NPTS + t] = xyz_last[t * 3 + 2];
  }
  {
    int o = t >> 7, c = t & 127;
    WT[0 * 16384 + c * 128 + o] = Wq[t];
    WT[1 * 16384 + c * 128 + o] = Wk[t];
    WT[2 * 16384 + c * 128 + o] = Wv[t];
    WT[3 * 16384 + c * 128 + o] = Wl[t];
  }
  if (t < 4864) stats_zero[t] = 0.f;
}

// ---------------- projections: Out = A @ W^T + b (8192x128 @ 128x128) ----------------
__global__ __launch_bounds__(256) void k_proj(const float* __restrict__ fea_i,
                                              const float* __restrict__ fea_last,
                                              const float* __restrict__ WT,
                                              const float* __restrict__ bq,
                                              const float* __restrict__ bk,
                                              const float* __restrict__ bv,
                                              float* __restrict__ Qo,
                                              float* __restrict__ Kpo,
                                              float* __restrict__ Vpo) {
  const int z = blockIdx.y;
  const float* A    = (z == 0) ? fea_last : fea_i;
  const float* WTz  = WT + z * 16384;
  const float* bias = (z == 0) ? bq : ((z == 1) ? bk : bv);
  float* Out        = (z == 0) ? Qo : ((z == 1) ? Kpo : Vpo);

  __shared__ unsigned short aT[128 * 72];    // [c][r], r<64, pad 72
  __shared__ unsigned short wT[128 * 128];   // [c][o] bf16
  const int t = threadIdx.x;
  const int rowbase = blockIdx.x * 64;
  {
    const int c = t & 127, half = t >> 7;
    #pragma unroll
    for (int i = 0; i < 16; ++i) {
      const int r = half * 32 + i * 2;
      float v0 = A[(size_t)(rowbase + r) * 128 + c];
      float v1 = A[(size_t)(rowbase + r + 1) * 128 + c];
      *(unsigned int*)&aT[c * 72 + r] = pack_bf2(v0, v1);
    }
    #pragma unroll
    for (int i = 0; i < 32; ++i) {
      const int e = i * 512 + t * 2;
      *(unsigned int*)&wT[e] = pack_bf2(WTz[e], WTz[e + 1]);
    }
  }
  __syncthreads();
  const int cg = t & 15, rg = t >> 4;
  const int p0 = cg * 8, r0 = rg * 4;
  float acc[4][8];
  #pragma unroll
  for (int i = 0; i < 4; ++i)
    #pragma unroll
    for (int j = 0; j < 8; ++j) acc[i][j] = 0.f;

  #pragma unroll 4
  for (int c = 0; c < 128; ++c) {
    uint2 au = *(const uint2*)&aT[c * 72 + r0];
    uint4 bu = *(const uint4*)&wT[c * 128 + p0];
    float a0, a1, a2, a3, b[8];
    unpack2(au.x, a0, a1); unpack2(au.y, a2, a3);
    unpack2(bu.x, b[0], b[1]); unpack2(bu.y, b[2], b[3]);
    unpack2(bu.z, b[4], b[5]); unpack2(bu.w, b[6], b[7]);
    #pragma unroll
    for (int j = 0; j < 8; ++j) {
      acc[0][j] = fmaf(a0, b[j], acc[0][j]);
      acc[1][j] = fmaf(a1, b[j], acc[1][j]);
      acc[2][j] = fmaf(a2, b[j], acc[2][j]);
      acc[3][j] = fmaf(a3, b[j], acc[3][j]);
    }
  }
  float bs[8];
  #pragma unroll
  for (int j = 0; j < 8; ++j) bs[j] = bias[p0 + j];
  #pragma unroll
  for (int i = 0; i < 4; ++i) {
    const int row = rowbase + r0 + i;
    float4 o0, o1;
    o0.x = acc[i][0] + bs[0]; o0.y = acc[i][1] + bs[1]; o0.z = acc[i][2] + bs[2]; o0.w = acc[i][3] + bs[3];
    o1.x = acc[i][4] + bs[4]; o1.y = acc[i][5] + bs[5]; o1.z = acc[i][6] + bs[6]; o1.w = acc[i][7] + bs[7];
    *(float4*)&Out[(size_t)row * 128 + p0]     = o0;
    *(float4*)&Out[(size_t)row * 128 + p0 + 4] = o1;
  }
}

// ---------------- fused KNN: gate -> LDS pool -> wave-min extraction ----------------
// One wave owns 4 queries. All 64 lanes scan all 8192 points with coalesced float4
// loads (xyzp is L2-resident), appending packed (dd,idx) u64 keys of in-radius points
// to per-query LDS pools. Top-16 extracted by 16 rounds of wave-wide u64 min-reduce;
// each lane only clears/rescans its own stride-64 slice (no intra-round syncs needed).
// Exactness: candidate ball radius has 8x volume margin over d16; n<16 or pool
// overflow falls back to an exact full scan (expected never on this data).
__global__ __launch_bounds__(256) void k_knn(const float* __restrict__ xyzT,
                                             const float4* __restrict__ xyzp,
                                             int* __restrict__ idxo) {
  __shared__ unsigned long long pool[QPB][CAPQ];
  __shared__ int cnt[QPB];
  const int t = threadIdx.x;
  const int lane = t & 63, wave = t >> 6;
  if (t < QPB) cnt[t] = 0;
  __syncthreads();

  const int qbase = blockIdx.x * QPB + wave * QPW;
  const int qq0 = wave * QPW;
  float qx[QPW], qy[QPW], qz[QPW];
  #pragma unroll
  for (int i = 0; i < QPW; ++i) {
    qx[i] = xyzT[3 * NPTS + qbase + i];
    qy[i] = xyzT[4 * NPTS + qbase + i];
    qz[i] = xyzT[5 * NPTS + qbase + i];
  }

  #pragma unroll 2
  for (int it = 0; it < NPTS / 64; ++it) {
    const int p = it * 64 + lane;
    const float4 pp = xyzp[p];
    #pragma unroll
    for (int i = 0; i < QPW; ++i) {
      float dx = qx[i] - pp.x, dy = qy[i] - pp.y, dz = qz[i] - pp.z;
      float dd = fmaf(dx, dx, fmaf(dy, dy, dz * dz));   // same formula as final ordering
      if (dd < KNN_T2) {
        unsigned long long key = ((unsigned long long)__float_as_uint(dd) << 32) | (unsigned int)p;
        int pos = atomicAdd(&cnt[qq0 + i], 1);
        if (pos < CAPQ) pool[qq0 + i][pos] = key;
      }
    }
  }
  __syncthreads();   // make each wave's scattered pool writes visible to all its lanes

  #pragma unroll 1
  for (int i = 0; i < QPW; ++i) {
    const int qq = qq0 + i;
    const int q = qbase + i;
    const int n = cnt[qq];
    if (n >= 16 && n <= CAPQ) {
      // per-lane local min over its slice {lane, lane+64, ...}
      unsigned long long mymin = ~0ull; int mypos = -1;
      for (int j = lane; j < n; j += 64) {
        unsigned long long k = pool[qq][j];
        if (k < mymin) { mymin = k; mypos = j; }
      }
      unsigned long long myout = ~0ull;
      #pragma unroll 1
      for (int r = 0; r < 16; ++r) {
        unsigned long long w = mymin;
        #pragma unroll
        for (int o = 32; o; o >>= 1) {
          unsigned long long u = __shfl_xor(w, o);
          w = (u < w) ? u : w;
        }
        if (mymin == w && mypos >= 0) {       // unique winner (keys carry distinct idx)
          pool[qq][mypos] = ~0ull;
          mymin = ~0ull; mypos = -1;
          for (int j = lane; j < n; j += 64) {
            unsigned long long k = pool[qq][j];
            if (k < mymin) { mymin = k; mypos = j; }
          }
        }
        if (lane == r) myout = w;
      }
      if (lane < 16) idxo[q * 16 + lane] = (int)(myout & 0xffffffffull);
    } else {
      // exact fallback: per-lane top-16 over its 128 points, then 16 wave-min rounds
      unsigned long long key[16];
      #pragma unroll
      for (int j = 0; j < 16; ++j) key[j] = ~0ull;
      for (int it = 0; it < NPTS / 64; ++it) {
        const int p = it * 64 + lane;
        const float4 pp = xyzp[p];
        float dx = qx[i] - pp.x, dy = qy[i] - pp.y, dz = qz[i] - pp.z;
        float dd = fmaf(dx, dx, fmaf(dy, dy, dz * dz));
        insert16(key, ((unsigned long long)__float_as_uint(dd) << 32) | (unsigned int)p);
      }
      unsigned long long myout = ~0ull;
      #pragma unroll 1
      for (int r = 0; r < 16; ++r) {
        unsigned long long w = key[0];
        #pragma unroll
        for (int o = 32; o; o >>= 1) {
          unsigned long long u = __shfl_xor(w, o);
          w = (u < w) ? u : w;
        }
        if (key[0] == w) {                    // winner shifts its sorted list down (static idx)
          #pragma unroll
          for (int j = 0; j < 15; ++j) key[j] = key[j + 1];
          key[15] = ~0ull;
        }
        if (lane == r) myout = w;
      }
      if (lane < 16) idxo[q * 16 + lane] = (int)(myout & 0xffffffffull);
    }
  }
}

// ---------------- stats1: per-channel sum/sumsq of w = Q[n] - Kp[idx] ----------------
__global__ __launch_bounds__(256) void k_stats1(const float* __restrict__ Q,
                                                const float* __restrict__ Kp,
                                                const int* __restrict__ idx,
                                                float* __restrict__ stats1) {
  const int t = threadIdx.x;
  const int o = t & 127, h = t >> 7;
  float s = 0.f, q2 = 0.f;
  const int base = blockIdx.x * 512;
  for (int i = 0; i < 256; ++i) {
    const int row = base + i * 2 + h;
    const int n = row >> 4;
    const int pid = idx[row];
    float w = Q[(size_t)n * 128 + o] - Kp[(size_t)pid * 128 + o];
    s += w; q2 += w * w;
  }
  __shared__ float rs[256], rq[256];
  rs[t] = s; rq[t] = q2;
  __syncthreads();
  if (t < 128) {
    atomicAdd(&stats1[o],       rs[t] + rs[t + 128]);
    atomicAdd(&stats1[128 + o], rq[t] + rq[t + 128]);
  }
}

// ---------------- BN finalize: scale/shift from (sum,sumsq) ----------------
__global__ void k_bnfin(const float* __restrict__ stats, int nrep, float invM,
                        const float* __restrict__ gamma, const float* __restrict__ beta,
                        float* __restrict__ bn) {
  const int o = threadIdx.x;  // 128
  float s = 0.f, q = 0.f;
  for (int r = 0; r < nrep; ++r) { s += stats[r * 256 + o]; q += stats[r * 256 + 128 + o]; }
  float mean = s * invM;
  float var  = fmaf(-mean, mean, q * invM);     // biased variance
  float sc = gamma[o] * rsqrtf(var + BN_EPS);
  bn[o]       = sc;
  bn[128 + o] = fmaf(-mean, sc, beta[o]);
}

// ---------------- mid GEMM: y = leaky(bn1(w)) @ Wl^T + bl ; + BN2 stats; y -> bf16 ----------------
__global__ __launch_bounds__(256) void k_mid(const float* __restrict__ Q,
                                             const float* __restrict__ Kp,
                                             const int* __restrict__ idx,
                                             const float* __restrict__ WTl,
                                             const float* __restrict__ bl,
                                             const float* __restrict__ bn1,
                                             float* __restrict__ stats2,
                                             unsigned short* __restrict__ Y) {
  __shared__ unsigned short aT[128 * 72];
  __shared__ unsigned short wT[128 * 128];
  __shared__ float red[4 * 16 * 16];
  const int t = threadIdx.x;
  const int rowbase = blockIdx.x * 64;
  {
    const int c = t & 127, half = t >> 7;
    const float s1 = bn1[c], sh1 = bn1[128 + c];
    #pragma unroll
    for (int i = 0; i < 16; ++i) {
      const int r = half * 32 + i * 2;
      const int g0 = rowbase + r, g1 = g0 + 1;
      const int n0 = g0 >> 4, n1 = g1 >> 4;
      const int pa = idx[g0], pb = idx[g1];
      float w0 = Q[(size_t)n0 * 128 + c] - Kp[(size_t)pa * 128 + c];
      float w1 = Q[(size_t)n1 * 128 + c] - Kp[(size_t)pb * 128 + c];
      float x0 = fmaf(w0, s1, sh1); x0 = (x0 >= 0.f) ? x0 : SLOPE * x0;
      float x1 = fmaf(w1, s1, sh1); x1 = (x1 >= 0.f) ? x1 : SLOPE * x1;
      *(unsigned int*)&aT[c * 72 + r] = pack_bf2(x0, x1);
    }
    #pragma unroll
    for (int i = 0; i < 32; ++i) {
      const int e = i * 512 + t * 2;
      *(unsigned int*)&wT[e] = pack_bf2(WTl[e], WTl[e + 1]);
    }
  }
  __syncthreads();
  const int cg = t & 15, rg = t >> 4;
  const int p0 = cg * 8, r0 = rg * 4;
  float acc[4][8];
  #pragma unroll
  for (int i = 0; i < 4; ++i)
    #pragma unroll
    for (int j = 0; j < 8; ++j) acc[i][j] = 0.f;

  #pragma unroll 4
  for (int c = 0; c < 128; ++c) {
    uint2 au = *(const uint2*)&aT[c * 72 + r0];
    uint4 bu = *(const uint4*)&wT[c * 128 + p0];
    float a0, a1, a2, a3, b[8];
    unpack2(au.x, a0, a1); unpack2(au.y, a2, a3);
    unpack2(bu.x, b[0], b[1]); unpack2(bu.y, b[2], b[3]);
    unpack2(bu.z, b[4], b[5]); unpack2(bu.w, b[6], b[7]);
    #pragma unroll
    for (int j = 0; j < 8; ++j) {
      acc[0][j] = fmaf(a0, b[j], acc[0][j]);
      acc[1][j] = fmaf(a1, b[j], acc[1][j]);
      acc[2][j] = fmaf(a2, b[j], acc[2][j]);
      acc[3][j] = fmaf(a3, b[j], acc[3][j]);
    }
  }
  float bs[8];
  #pragma unroll
  for (int j = 0; j < 8; ++j) bs[j] = bl[p0 + j];
  float ssum[8], sqq[8];
  #pragma unroll
  for (int j = 0; j < 8; ++j) { ssum[j] = 0.f; sqq[j] = 0.f; }
  #pragma unroll
  for (int i = 0; i < 4; ++i) {
    float zv[8];
    #pragma unroll
    for (int j = 0; j < 8; ++j) { zv[j] = acc[i][j] + bs[j]; ssum[j] += zv[j]; sqq[j] += zv[j] * zv[j]; }
    uint4 st;
    st.x = pack_bf2(zv[0], zv[1]); st.y = pack_bf2(zv[2], zv[3]);
    st.z = pack_bf2(zv[4], zv[5]); st.w = pack_bf2(zv[6], zv[7]);
    *(uint4*)&Y[(size_t)(rowbase + r0 + i) * 128 + p0] = st;
  }
  #pragma unroll
  for (int j = 0; j < 8; ++j) {
    ssum[j] += __shfl_xor(ssum[j], 16); ssum[j] += __shfl_xor(ssum[j], 32);
    sqq[j]  += __shfl_xor(sqq[j], 16);  sqq[j]  += __shfl_xor(sqq[j], 32);
  }
  const int lane = t & 63, wave = t >> 6;
  if (lane < 16) {
    #pragma unroll
    for (int j = 0; j < 8; ++j) {
      red[(wave * 16 + lane) * 16 + j]     = ssum[j];
      red[(wave * 16 + lane) * 16 + 8 + j] = sqq[j];
    }
  }
  __syncthreads();
  {
    const int cg2 = t >> 4, v = t & 15;
    float tot = red[(0 * 16 + cg2) * 16 + v] + red[(1 * 16 + cg2) * 16 + v]
              + red[(2 * 16 + cg2) * 16 + v] + red[(3 * 16 + cg2) * 16 + v];
    const int p = cg2 * 8 + (v & 7);
    const int stat = v >> 3;
    atomicAdd(&stats2[(blockIdx.x & 15) * 256 + stat * 128 + p], tot);
  }
}

// ---------------- epilogue: BN2+leaky -> softmax over K -> weighted V gather ----------------
__global__ __launch_bounds__(128) void k_epi(const unsigned short* __restrict__ Y,
                                             const float* __restrict__ Vp,
                                             const int* __restrict__ idx,
                                             const float* __restrict__ bn2,
                                             float* __restrict__ out) {
  const int n = blockIdx.x;
  const int p = threadIdx.x;
  const float s2 = bn2[p], sh2 = bn2[128 + p];
  float z[16];
  #pragma unroll
  for (int k = 0; k < 16; ++k) {
    float yv = bf2f(Y[(size_t)(n * 16 + k) * 128 + p]);
    float v = fmaf(yv, s2, sh2);
    z[k] = (v >= 0.f) ? v : SLOPE * v;
  }
  float m = z[0];
  #pragma unroll
  for (int k = 1; k < 16; ++k) m = fmaxf(m, z[k]);
  float acc = 0.f, denom = 0.f;
  #pragma unroll
  for (int k = 0; k < 16; ++k) {
    float e = __expf(z[k] - m);
    denom += e;
    const int pid = idx[n * 16 + k];
    acc = fmaf(e, Vp[(size_t)pid * 128 + p], acc);
  }
  out[(size_t)n * 128 + p] = acc / denom;
}

extern "C" void kernel_launch(void* const* d_in, const int* in_sizes, int n_in,
                              void* d_out, int out_size, void* d_ws, size_t ws_size,
                              hipStream_t stream) {
  const float* fea_i    = (const float*)d_in[0];
  const float* fea_last = (const float*)d_in[1];
  const float* xyz_i    = (const float*)d_in[2];
  const float* xyz_last = (const float*)d_in[3];
  // d_in[4] = batch (single batch, unused)
  const float* Wq = (const float*)d_in[5];
  const float* bq = (const float*)d_in[6];
  const float* Wk = (const float*)d_in[7];
  const float* bk = (const float*)d_in[8];
  const float* Wv = (const float*)d_in[9];
  const float* bv = (const float*)d_in[10];
  const float* g1 = (const float*)d_in[11];
  const float* b1 = (const float*)d_in[12];
  const float* Wl = (const float*)d_in[13];
  const float* bl = (const float*)d_in[14];
  const float* g2 = (const float*)d_in[15];
  const float* b2 = (const float*)d_in[16];

  if (ws_size < (size_t)WS_NEED) return;

  char* ws = (char*)d_ws;
  float*  Q      = (float*)(ws + OFF_Q);
  float*  Kp     = (float*)(ws + OFF_KP);
  float*  Vp     = (float*)(ws + OFF_VP);
  float*  WT     = (float*)(ws + OFF_WT);
  float*  xyzT   = (float*)(ws + OFF_XYZT);
  int*    idxb   = (int*)  (ws + OFF_IDX);
  float*  stats1 = (float*)(ws + OFF_STATS);
  float*  bn1    = stats1 + 256;
  float*  stats2 = stats1 + 512;
  float*  bn2    = stats1 + 512 + 4096;
  float4* xyzp   = (float4*)(ws + OFF_BIG);             // dead after k_knn
  unsigned short* Y = (unsigned short*)(ws + OFF_BIG);  // aliases xyzp (k_mid runs after k_knn)

  k_prep<<<64, 256, 0, stream>>>(xyz_i, xyz_last, Wq, Wk, Wv, Wl, xyzT, xyzp, WT, stats1);
  k_proj<<<dim3(128, 3), 256, 0, stream>>>(fea_i, fea_last, WT, bq, bk, bv, Q, Kp, Vp);
  k_knn<<<NPTS / QPB, 256, 0, stream>>>(xyzT, xyzp, idxb);
  k_stats1<<<256, 256, 0, stream>>>(Q, Kp, idxb, stats1);
  k_bnfin<<<1, 128, 0, stream>>>(stats1, 1, 1.f / (float)NROWS, g1, b1, bn1);
  k_mid<<<2048, 256, 0, stream>>>(Q, Kp, idxb, WT + 3 * 16384, bl, bn1, stats2, Y);
  k_bnfin<<<1, 128, 0, stream>>>(stats2, 16, 1.f / (float)NROWS, g2, b2, bn2);
  k_epi<<<8192, 128, 0, stream>>>(Y, Vp, idxb, bn2, (float*)d_out);
}

// Round 7
// 190.864 us; speedup vs baseline: 3.2784x; 1.3790x over previous
//
#include <hip/hip_runtime.h>
#include <stdint.h>

#define NPTS   8192
#define NROWS  (NPTS * 16)
#define SLOPE  0.01f
#define BN_EPS 1e-5f

// fused KNN parameters
#define KNN_T2 0.04f   // gate radius T=0.2 ; corner-query d16 ~ 0.155 -> 2.1x volume margin
#define CAPQ   408     // per-query candidate pool cap (lambda<=275, +8 sigma); overflow -> exact fallback
#define QPB    8       // queries per block (256 thr = 4 waves x 2 queries)
#define QPW    2       // queries per wave

// ---- workspace layout (bytes) ----
#define OFF_Q      0u          // 8192x128 f32  (fea_last @ Wq^T + bq)
#define OFF_KP     4194304u    // 8192x128 f32
#define OFF_VP     8388608u    // 8192x128 f32
#define OFF_WT     12582912u   // 4 x 128x128 f32 transposed (q,k,v used)
#define OFF_XYZT   12845056u   // 6 x 8192 f32: xi yi zi | xl yl zl
#define OFF_IDX    13041664u   // 131072 i32 (8192 x 16 neighbor ids)
#define OFF_STATS  13565952u   // 4864 f32: stats1[256] bn1[256] stats2[16*256] bn2[256]
#define OFF_BIG    13585408u   // xyzp (128KB, dead after knn), later aliased by Y bf16 (33.5MB)
#define WS_NEED    47139840u

typedef __bf16 bf16x8 __attribute__((ext_vector_type(8)));
typedef float  f32x4  __attribute__((ext_vector_type(4)));

__device__ __forceinline__ unsigned int pack_bf2(float lo, float hi) {
  unsigned int a = __float_as_uint(lo);
  unsigned int b = __float_as_uint(hi);
  unsigned int ra = (a + 0x7fffu + ((a >> 16) & 1u)) >> 16;           // RNE bf16 of lo
  unsigned int rb = (b + 0x7fffu + ((b >> 16) & 1u)) & 0xffff0000u;   // RNE bf16 of hi in high half
  return ra | rb;
}
__device__ __forceinline__ unsigned short bf1(float v) {
  unsigned int a = __float_as_uint(v);
  return (unsigned short)((a + 0x7fffu + ((a >> 16) & 1u)) >> 16);
}
__device__ __forceinline__ void unpack2(unsigned int u, float& lo, float& hi) {
  lo = __uint_as_float(u << 16);
  hi = __uint_as_float(u & 0xffff0000u);
}
__device__ __forceinline__ float bf2f(unsigned short u) {
  return __uint_as_float(((unsigned int)u) << 16);
}

__device__ __forceinline__ void insert16(unsigned long long* key, unsigned long long kk) {
  if (kk < key[15]) {
    #pragma unroll
    for (int u = 15; u >= 1; --u) {
      bool cm1 = kk < key[u - 1];
      bool cs  = kk < key[u];
      key[u] = cm1 ? key[u - 1] : (cs ? kk : key[u]);
    }
    key[0] = (kk < key[0]) ? kk : key[0];
  }
}

// ---------------- prep: transpose xyz + weights, build (x,y,z,|p|^2), zero stats ----------------
__global__ __launch_bounds__(256) void k_prep(const float* __restrict__ xyz_i,
                                              const float* __restrict__ xyz_last,
                                              const float* __restrict__ Wq,
                                              const float* __restrict__ Wk,
                                              const float* __restrict__ Wv,
                                              float* __restrict__ xyzT,
                                              float4* __restrict__ xyzp,
                                              float* __restrict__ WT,
                                              float* __restrict__ stats_zero) {
  int t = blockIdx.x * 256 + threadIdx.x;   // 16384 threads
  if (t < NPTS) {
    float x = xyz_i[t * 3 + 0], y = xyz_i[t * 3 + 1], z = xyz_i[t * 3 + 2];
    xyzT[0 * NPTS + t] = x;
    xyzT[1 * NPTS + t] = y;
    xyzT[2 * NPTS + t] = z;
    xyzp[t] = make_float4(x, y, z, fmaf(x, x, fmaf(y, y, z * z)));
    xyzT[3 * NPTS + t] = xyz_last[t * 3 + 0];
    xyzT[4 * NPTS + t] = xyz_last[t * 3 + 1];
    xyzT[5 * NPTS + t] = xyz_last[t * 3 + 2];
  }
  {
    int o = t >> 7, c = t & 127;
    WT[0 * 16384 + c * 128 + o] = Wq[t];
    WT[1 * 16384 + c * 128 + o] = Wk[t];
    WT[2 * 16384 + c * 128 + o] = Wv[t];
  }
  if (t < 4864) stats_zero[t] = 0.f;
}

// ---------------- projections: Out = A @ W^T + b (8192x128 @ 128x128) ----------------
__global__ __launch_bounds__(256) void k_proj(const float* __restrict__ fea_i,
                                              const float* __restrict__ fea_last,
                                              const float* __restrict__ WT,
                                              const float* __restrict__ bq,
                                              const float* __restrict__ bk,
                                              const float* __restrict__ bv,
                                              float* __restrict__ Qo,
                                              float* __restrict__ Kpo,
                                              float* __restrict__ Vpo) {
  const int z = blockIdx.y;
  const float* A    = (z == 0) ? fea_last : fea_i;
  const float* WTz  = WT + z * 16384;
  const float* bias = (z == 0) ? bq : ((z == 1) ? bk : bv);
  float* Out        = (z == 0) ? Qo : ((z == 1) ? Kpo : Vpo);

  __shared__ unsigned short aT[128 * 72];    // [c][r], r<64, pad 72
  __shared__ unsigned short wT[128 * 128];   // [c][o] bf16
  const int t = threadIdx.x;
  const int rowbase = blockIdx.x * 64;
  {
    const int c = t & 127, half = t >> 7;
    #pragma unroll
    for (int i = 0; i < 16; ++i) {
      const int r = half * 32 + i * 2;
      float v0 = A[(size_t)(rowbase + r) * 128 + c];
      float v1 = A[(size_t)(rowbase + r + 1) * 128 + c];
      *(unsigned int*)&aT[c * 72 + r] = pack_bf2(v0, v1);
    }
    #pragma unroll
    for (int i = 0; i < 32; ++i) {
      const int e = i * 512 + t * 2;
      *(unsigned int*)&wT[e] = pack_bf2(WTz[e], WTz[e + 1]);
    }
  }
  __syncthreads();
  const int cg = t & 15, rg = t >> 4;
  const int p0 = cg * 8, r0 = rg * 4;
  float acc[4][8];
  #pragma unroll
  for (int i = 0; i < 4; ++i)
    #pragma unroll
    for (int j = 0; j < 8; ++j) acc[i][j] = 0.f;

  #pragma unroll 4
  for (int c = 0; c < 128; ++c) {
    uint2 au = *(const uint2*)&aT[c * 72 + r0];
    uint4 bu = *(const uint4*)&wT[c * 128 + p0];
    float a0, a1, a2, a3, b[8];
    unpack2(au.x, a0, a1); unpack2(au.y, a2, a3);
    unpack2(bu.x, b[0], b[1]); unpack2(bu.y, b[2], b[3]);
    unpack2(bu.z, b[4], b[5]); unpack2(bu.w, b[6], b[7]);
    #pragma unroll
    for (int j = 0; j < 8; ++j) {
      acc[0][j] = fmaf(a0, b[j], acc[0][j]);
      acc[1][j] = fmaf(a1, b[j], acc[1][j]);
      acc[2][j] = fmaf(a2, b[j], acc[2][j]);
      acc[3][j] = fmaf(a3, b[j], acc[3][j]);
    }
  }
  float bs[8];
  #pragma unroll
  for (int j = 0; j < 8; ++j) bs[j] = bias[p0 + j];
  #pragma unroll
  for (int i = 0; i < 4; ++i) {
    const int row = rowbase + r0 + i;
    float4 o0, o1;
    o0.x = acc[i][0] + bs[0]; o0.y = acc[i][1] + bs[1]; o0.z = acc[i][2] + bs[2]; o0.w = acc[i][3] + bs[3];
    o1.x = acc[i][4] + bs[4]; o1.y = acc[i][5] + bs[5]; o1.z = acc[i][6] + bs[6]; o1.w = acc[i][7] + bs[7];
    *(float4*)&Out[(size_t)row * 128 + p0]     = o0;
    *(float4*)&Out[(size_t)row * 128 + p0 + 4] = o1;
  }
}

// ---------------- fused KNN: ballot-append gate -> register-slice tournament ----------------
// One wave owns 2 queries. Scan: 64 lanes stream all 8192 points (L2-resident float4),
// gated candidates appended deterministically via ballot+mbcnt (no atomics, no barrier --
// pools are wave-private). Extraction: each lane sorts its stride-64 pool slice (len<=7)
// into registers; 16 rounds of wave-min on the heads via fmin(f64) butterfly (positive-f64
// order == u64 order; ~0ull is NaN -> loses to everything). Winner pop = register select.
// Exact: same fmaf distance formula as reference ordering; n<16 or overflow -> full-scan fallback.
__global__ __launch_bounds__(256) void k_knn(const float* __restrict__ xyzT,
                                             const float4* __restrict__ xyzp,
                                             int* __restrict__ idxo) {
  __shared__ unsigned long long pool[QPB][CAPQ];   // 8*408*8 = 26112 B
  const int t = threadIdx.x;
  const int lane = t & 63, wave = t >> 6;
  const int qq0 = wave * QPW;
  const int qbase = blockIdx.x * QPB + qq0;

  float qx[QPW], qy[QPW], qz[QPW];
  #pragma unroll
  for (int i = 0; i < QPW; ++i) {
    qx[i] = xyzT[3 * NPTS + qbase + i];
    qy[i] = xyzT[4 * NPTS + qbase + i];
    qz[i] = xyzT[5 * NPTS + qbase + i];
  }
  int cnt[QPW];
  #pragma unroll
  for (int i = 0; i < QPW; ++i) cnt[i] = 0;

  const unsigned long long below = (1ull << lane) - 1ull;
  #pragma unroll 2
  for (int it = 0; it < NPTS / 64; ++it) {
    const int p = it * 64 + lane;
    const float4 pp = xyzp[p];
    #pragma unroll
    for (int i = 0; i < QPW; ++i) {
      float dx = qx[i] - pp.x, dy = qy[i] - pp.y, dz = qz[i] - pp.z;
      float dd = fmaf(dx, dx, fmaf(dy, dy, dz * dz));   // exact reference-ordering formula
      bool g = dd < KNN_T2;
      unsigned long long mask = __ballot(g);
      int pos = cnt[i] + (int)__popcll(mask & below);
      if (g && pos < CAPQ)
        pool[qq0 + i][pos] = ((unsigned long long)__float_as_uint(dd) << 32) | (unsigned int)p;
      cnt[i] += (int)__popcll(mask);
    }
  }
  // no __syncthreads: pools are wave-private; in-wave DS ordering + lgkmcnt suffice

  #pragma unroll 1
  for (int i = 0; i < QPW; ++i) {
    const int qq = qq0 + i;
    const int q = qbase + i;
    const int n = cnt[i];
    if (n >= 16 && n <= CAPQ) {
      // build per-lane sorted slice list: positions {lane, lane+64, ...}, len <= ceil(408/64)=7
      unsigned long long lst[7];
      #pragma unroll
      for (int j = 0; j < 7; ++j) lst[j] = ~0ull;
      for (int j = lane; j < n; j += 64) {
        unsigned long long kk = pool[qq][j];
        #pragma unroll
        for (int u = 6; u >= 1; --u) {
          bool cm1 = kk < lst[u - 1];
          bool cs  = kk < lst[u];
          lst[u] = cm1 ? lst[u - 1] : (cs ? kk : lst[u]);
        }
        lst[0] = (kk < lst[0]) ? kk : lst[0];
      }
      unsigned long long myout = ~0ull;
      #pragma unroll 1
      for (int r = 0; r < 16; ++r) {
        double h = __longlong_as_double((long long)lst[0]);
        #pragma unroll
        for (int o = 32; o; o >>= 1) {
          double u = __shfl_xor(h, o);
          h = fmin(h, u);          // NaN (empty sentinel) loses; positive-f64 order == u64 order
        }
        unsigned long long wmin = (unsigned long long)__double_as_longlong(h);
        bool win = (lst[0] == wmin);   // unique winner: keys carry distinct idx
        #pragma unroll
        for (int j = 0; j < 6; ++j) lst[j] = win ? lst[j + 1] : lst[j];
        lst[6] = win ? ~0ull : lst[6];
        if (lane == r) myout = wmin;
      }
      if (lane < 16) idxo[q * 16 + lane] = (int)(myout & 0xffffffffull);
    } else {
      // exact fallback: per-lane top-16 over its 128 points, then 16 wave-min rounds
      unsigned long long key[16];
      #pragma unroll
      for (int j = 0; j < 16; ++j) key[j] = ~0ull;
      for (int it = 0; it < NPTS / 64; ++it) {
        const int p = it * 64 + lane;
        const float4 pp = xyzp[p];
        float dx = qx[i] - pp.x, dy = qy[i] - pp.y, dz = qz[i] - pp.z;
        float dd = fmaf(dx, dx, fmaf(dy, dy, dz * dz));
        insert16(key, ((unsigned long long)__float_as_uint(dd) << 32) | (unsigned int)p);
      }
      unsigned long long myout = ~0ull;
      #pragma unroll 1
      for (int r = 0; r < 16; ++r) {
        unsigned long long w = key[0];
        #pragma unroll
        for (int o = 32; o; o >>= 1) {
          unsigned long long u = __shfl_xor(w, o);
          w = (u < w) ? u : w;
        }
        if (key[0] == w) {
          #pragma unroll
          for (int j = 0; j < 15; ++j) key[j] = key[j + 1];
          key[15] = ~0ull;
        }
        if (lane == r) myout = w;
      }
      if (lane < 16) idxo[q * 16 + lane] = (int)(myout & 0xffffffffull);
    }
  }
}

// ---------------- stats1: per-channel sum/sumsq of w = Q[n] - Kp[idx] ----------------
__global__ __launch_bounds__(256) void k_stats1(const float* __restrict__ Q,
                                                const float* __restrict__ Kp,
                                                const int* __restrict__ idx,
                                                float* __restrict__ stats1) {
  const int t = threadIdx.x;
  const int o = t & 127, h = t >> 7;
  float s = 0.f, q2 = 0.f;
  const int base = blockIdx.x * 512;
  for (int i = 0; i < 256; ++i) {
    const int row = base + i * 2 + h;
    const int n = row >> 4;
    const int pid = idx[row];
    float w = Q[(size_t)n * 128 + o] - Kp[(size_t)pid * 128 + o];
    s += w; q2 += w * w;
  }
  __shared__ float rs[256], rq[256];
  rs[t] = s; rq[t] = q2;
  __syncthreads();
  if (t < 128) {
    atomicAdd(&stats1[o],       rs[t] + rs[t + 128]);
    atomicAdd(&stats1[128 + o], rq[t] + rq[t + 128]);
  }
}

// ---------------- BN finalize: scale/shift from (sum,sumsq) ----------------
__global__ void k_bnfin(const float* __restrict__ stats, int nrep, float invM,
                        const float* __restrict__ gamma, const float* __restrict__ beta,
                        float* __restrict__ bn) {
  const int o = threadIdx.x;  // 128
  float s = 0.f, q = 0.f;
  for (int r = 0; r < nrep; ++r) { s += stats[r * 256 + o]; q += stats[r * 256 + 128 + o]; }
  float mean = s * invM;
  float var  = fmaf(-mean, mean, q * invM);     // biased variance
  float sc = gamma[o] * rsqrtf(var + BN_EPS);
  bn[o]       = sc;
  bn[128 + o] = fmaf(-mean, sc, beta[o]);
}

// ---------------- mid GEMM via MFMA: y = leaky(bn1(Q[n]-Kp[idx])) @ Wl^T + bl ----------------
// block = 4 waves, 64 rows (4 queries; wave w owns query n=4*bid+w, its 16 neighbor rows).
// A-frag built in registers from gather (lane row = lane&15 = neighbor slot, k = (lane>>4)*8+j).
// Wl staged once in LDS bf16 with (p&7)<<4 XOR swizzle (T2: 16 rows x same 16B col otherwise
// 16-way conflicts). C/D layout: col=lane&15, row=(lane>>4)*4+reg. Epilogue reuses dead Wl LDS
// for coalesced bf16 Y stores + block stats2 reduction.
__global__ __launch_bounds__(256) void k_mid(const float* __restrict__ Q,
                                             const float* __restrict__ Kp,
                                             const int* __restrict__ idx,
                                             const float* __restrict__ Wl,
                                             const float* __restrict__ bl,
                                             const float* __restrict__ bn1,
                                             float* __restrict__ stats2,
                                             unsigned short* __restrict__ Y) {
  __shared__ union {
    unsigned short wl[128 * 128];                 // 32 KB swizzled bf16 Wl
    struct {
      unsigned short stage[64][136];              // 17408 B Y staging (272B rows, 16B-aligned)
      float red[4 * 256];                         // 4 KB per-wave stats partials
    } ep;
  } sm;

  const int t = threadIdx.x;
  const int lane = t & 63, w = t >> 6;
  const int rowbase = blockIdx.x * 64;

  // stage Wl (f32 [p][c] row-major) -> LDS bf16, 16B chunks, XOR-swizzled
  #pragma unroll
  for (int i = 0; i < 8; ++i) {
    const int chunk = i * 256 + t;                // 2048 chunks of 8 c's
    const int p = chunk >> 4, cseg = chunk & 15;
    const float4 wa = *(const float4*)(Wl + (size_t)p * 128 + cseg * 8);
    const float4 wb = *(const float4*)(Wl + (size_t)p * 128 + cseg * 8 + 4);
    uint4 pk;
    pk.x = pack_bf2(wa.x, wa.y); pk.y = pack_bf2(wa.z, wa.w);
    pk.z = pack_bf2(wb.x, wb.y); pk.w = pack_bf2(wb.z, wb.w);
    *(uint4*)((char*)sm.wl + p * 256 + ((cseg * 16) ^ ((p & 7) << 4))) = pk;
  }
  __syncthreads();

  const int n = blockIdx.x * 4 + w;
  const int kslot = lane & 15;      // A row (neighbor slot) / B col within tile
  const int kgrp  = lane >> 4;      // k-group 0..3
  const int pid = idx[n * 16 + kslot];
  const float* Qrow = Q + (size_t)n * 128;
  const float* Krow = Kp + (size_t)pid * 128;

  f32x4 acc[8];
  #pragma unroll
  for (int tt = 0; tt < 8; ++tt) acc[tt] = (f32x4){0.f, 0.f, 0.f, 0.f};

  #pragma unroll
  for (int s = 0; s < 4; ++s) {
    const int c0 = s * 32 + kgrp * 8;
    const float4 qa = *(const float4*)(Qrow + c0);
    const float4 qb = *(const float4*)(Qrow + c0 + 4);
    const float4 ka = *(const float4*)(Krow + c0);
    const float4 kb = *(const float4*)(Krow + c0 + 4);
    const float4 sa = *(const float4*)(bn1 + c0);
    const float4 sb = *(const float4*)(bn1 + c0 + 4);
    const float4 ha = *(const float4*)(bn1 + 128 + c0);
    const float4 hb = *(const float4*)(bn1 + 128 + c0 + 4);
    float x[8];
    x[0] = fmaf(qa.x - ka.x, sa.x, ha.x);
    x[1] = fmaf(qa.y - ka.y, sa.y, ha.y);
    x[2] = fmaf(qa.z - ka.z, sa.z, ha.z);
    x[3] = fmaf(qa.w - ka.w, sa.w, ha.w);
    x[4] = fmaf(qb.x - kb.x, sb.x, hb.x);
    x[5] = fmaf(qb.y - kb.y, sb.y, hb.y);
    x[6] = fmaf(qb.z - kb.z, sb.z, hb.z);
    x[7] = fmaf(qb.w - kb.w, sb.w, hb.w);
    uint4 af;
    af.x = pack_bf2(fmaxf(x[0], SLOPE * x[0]), fmaxf(x[1], SLOPE * x[1]));
    af.y = pack_bf2(fmaxf(x[2], SLOPE * x[2]), fmaxf(x[3], SLOPE * x[3]));
    af.z = pack_bf2(fmaxf(x[4], SLOPE * x[4]), fmaxf(x[5], SLOPE * x[5]));
    af.w = pack_bf2(fmaxf(x[6], SLOPE * x[6]), fmaxf(x[7], SLOPE * x[7]));
    const bf16x8 A = __builtin_bit_cast(bf16x8, af);
    const int cbyte = s * 64 + kgrp * 16;
    #pragma unroll
    for (int tt = 0; tt < 8; ++tt) {
      const int prow = tt * 16 + kslot;
      const uint4 bw = *(const uint4*)((const char*)sm.wl + prow * 256 + (cbyte ^ ((prow & 7) << 4)));
      acc[tt] = __builtin_amdgcn_mfma_f32_16x16x32_bf16(A, __builtin_bit_cast(bf16x8, bw), acc[tt], 0, 0, 0);
    }
  }
  __syncthreads();   // all waves done reading sm.wl -> safe to reuse as ep

  // bias + per-col stats + bf16 staging
  #pragma unroll
  for (int tt = 0; tt < 8; ++tt) {
    const int col = tt * 16 + kslot;
    const float bb = bl[col];
    float s = 0.f, q2 = 0.f;
    #pragma unroll
    for (int r = 0; r < 4; ++r) {
      const float v = acc[tt][r] + bb;
      s += v; q2 += v * v;
      sm.ep.stage[w * 16 + kgrp * 4 + r][col] = bf1(v);
    }
    s  += __shfl_xor(s, 16);  s  += __shfl_xor(s, 32);
    q2 += __shfl_xor(q2, 16); q2 += __shfl_xor(q2, 32);
    if (kgrp == 0) {
      sm.ep.red[w * 256 + col]       = s;
      sm.ep.red[w * 256 + 128 + col] = q2;
    }
  }
  __syncthreads();

  // cooperative coalesced Y store (16B per thread per iter)
  #pragma unroll
  for (int i = 0; i < 4; ++i) {
    const int chunk = i * 256 + t;                // 1024 chunks
    const int row = chunk >> 4, cc = chunk & 15;
    const uint4 v = *(const uint4*)&sm.ep.stage[row][cc * 8];
    *(uint4*)&Y[(size_t)(rowbase + row) * 128 + cc * 8] = v;
  }
  // block stats2 reduction: t = stat*128 + col
  {
    const float tot = sm.ep.red[t] + sm.ep.red[256 + t] + sm.ep.red[512 + t] + sm.ep.red[768 + t];
    atomicAdd(&stats2[(blockIdx.x & 15) * 256 + t], tot);
  }
}

// ---------------- epilogue: BN2+leaky -> softmax over K -> weighted V gather ----------------
__global__ __launch_bounds__(128) void k_epi(const unsigned short* __restrict__ Y,
                                             const float* __restrict__ Vp,
                                             const int* __restrict__ idx,
                                             const float* __restrict__ bn2,
                                             float* __restrict__ out) {
  const int n = blockIdx.x;
  const int p = threadIdx.x;
  const float s2 = bn2[p], sh2 = bn2[128 + p];
  float z[16];
  #pragma unroll
  for (int k = 0; k < 16; ++k) {
    float yv = bf2f(Y[(size_t)(n * 16 + k) * 128 + p]);
    float v = fmaf(yv, s2, sh2);
    z[k] = (v >= 0.f) ? v : SLOPE * v;
  }
  float m = z[0];
  #pragma unroll
  for (int k = 1; k < 16; ++k) m = fmaxf(m, z[k]);
  float acc = 0.f, denom = 0.f;
  #pragma unroll
  for (int k = 0; k < 16; ++k) {
    float e = __expf(z[k] - m);
    denom += e;
    const int pid = idx[n * 16 + k];
    acc = fmaf(e, Vp[(size_t)pid * 128 + p], acc);
  }
  out[(size_t)n * 128 + p] = acc / denom;
}

extern "C" void kernel_launch(void* const* d_in, const int* in_sizes, int n_in,
                              void* d_out, int out_size, void* d_ws, size_t ws_size,
                              hipStream_t stream) {
  const float* fea_i    = (const float*)d_in[0];
  const float* fea_last = (const float*)d_in[1];
  const float* xyz_i    = (const float*)d_in[2];
  const float* xyz_last = (const float*)d_in[3];
  // d_in[4] = batch (single batch, unused)
  const float* Wq = (const float*)d_in[5];
  const float* bq = (const float*)d_in[6];
  const float* Wk = (const float*)d_in[7];
  const float* bk = (const float*)d_in[8];
  const float* Wv = (const float*)d_in[9];
  const float* bv = (const float*)d_in[10];
  const float* g1 = (const float*)d_in[11];
  const float* b1 = (const float*)d_in[12];
  const float* Wl = (const float*)d_in[13];
  const float* bl = (const float*)d_in[14];
  const float* g2 = (const float*)d_in[15];
  const float* b2 = (const float*)d_in[16];

  if (ws_size < (size_t)WS_NEED) return;

  char* ws = (char*)d_ws;
  float*  Q      = (float*)(ws + OFF_Q);
  float*  Kp     = (float*)(ws + OFF_KP);
  float*  Vp     = (float*)(ws + OFF_VP);
  float*  WT     = (float*)(ws + OFF_WT);
  float*  xyzT   = (float*)(ws + OFF_XYZT);
  int*    idxb   = (int*)  (ws + OFF_IDX);
  float*  stats1 = (float*)(ws + OFF_STATS);
  float*  bn1    = stats1 + 256;
  float*  stats2 = stats1 + 512;
  float*  bn2    = stats1 + 512 + 4096;
  float4* xyzp   = (float4*)(ws + OFF_BIG);             // dead after k_knn
  unsigned short* Y = (unsigned short*)(ws + OFF_BIG);  // aliases xyzp (k_mid runs after k_knn)

  k_prep<<<64, 256, 0, stream>>>(xyz_i, xyz_last, Wq, Wk, Wv, xyzT, xyzp, WT, stats1);
  k_proj<<<dim3(128, 3), 256, 0, stream>>>(fea_i, fea_last, WT, bq, bk, bv, Q, Kp, Vp);
  k_knn<<<NPTS / QPB, 256, 0, stream>>>(xyzT, xyzp, idxb);
  k_stats1<<<256, 256, 0, stream>>>(Q, Kp, idxb, stats1);
  k_bnfin<<<1, 128, 0, stream>>>(stats1, 1, 1.f / (float)NROWS, g1, b1, bn1);
  k_mid<<<2048, 256, 0, stream>>>(Q, Kp, idxb, Wl, bl, bn1, stats2, Y);
  k_bnfin<<<1, 128, 0, stream>>>(stats2, 16, 1.f / (float)NROWS, g2, b2, bn2);
  k_epi<<<8192, 128, 0, stream>>>(Y, Vp, idxb, bn2, (float*)d_out);
}

// Round 8
// 183.563 us; speedup vs baseline: 3.4088x; 1.0398x over previous
//
#include <hip/hip_runtime.h>
#include <stdint.h>

#define NPTS   8192
#define NROWS  (NPTS * 16)
#define SLOPE  0.01f
#define BN_EPS 1e-5f

// fused KNN parameters
#define KNN_T2 0.04f   // gate radius T=0.2 ; corner-query d16 ~ 0.155 -> 2.1x volume margin
#define CAPQ   408     // per-query candidate pool cap (lambda<=275, +8 sigma); overflow -> exact fallback
#define QPB    4       // queries per block (256 thr = 4 waves x 1 query) -> 2048 blocks, 8 blk/CU
#define QPW    1       // queries per wave

// ---- workspace layout (bytes) ----
#define OFF_Q      0u          // 8192x128 f32  (fea_last @ Wq^T + bq)
#define OFF_KP     4194304u    // 8192x128 f32
#define OFF_VP     8388608u    // 8192x128 f32
#define OFF_XYZT   12845056u   // 6 x 8192 f32: xi yi zi | xl yl zl (only 3..5 used)
#define OFF_IDX    13041664u   // 131072 i32 (8192 x 16 neighbor ids)
#define OFF_STATS  13565952u   // 4864 f32: stats1[256] bn1[256] stats2[16*256] bn2[256]
#define OFF_BIG    13585408u   // xyzp (128KB, dead after knn), later aliased by Y bf16 (33.5MB)
#define WS_NEED    47139840u

typedef __bf16 bf16x8 __attribute__((ext_vector_type(8)));
typedef float  f32x4  __attribute__((ext_vector_type(4)));

__device__ __forceinline__ unsigned int pack_bf2(float lo, float hi) {
  unsigned int a = __float_as_uint(lo);
  unsigned int b = __float_as_uint(hi);
  unsigned int ra = (a + 0x7fffu + ((a >> 16) & 1u)) >> 16;           // RNE bf16 of lo
  unsigned int rb = (b + 0x7fffu + ((b >> 16) & 1u)) & 0xffff0000u;   // RNE bf16 of hi in high half
  return ra | rb;
}
__device__ __forceinline__ unsigned short bf1(float v) {
  unsigned int a = __float_as_uint(v);
  return (unsigned short)((a + 0x7fffu + ((a >> 16) & 1u)) >> 16);
}
__device__ __forceinline__ float bf2f(unsigned short u) {
  return __uint_as_float(((unsigned int)u) << 16);
}

__device__ __forceinline__ void insert16(unsigned long long* key, unsigned long long kk) {
  if (kk < key[15]) {
    #pragma unroll
    for (int u = 15; u >= 1; --u) {
      bool cm1 = kk < key[u - 1];
      bool cs  = kk < key[u];
      key[u] = cm1 ? key[u - 1] : (cs ? kk : key[u]);
    }
    key[0] = (kk < key[0]) ? kk : key[0];
  }
}

// ---------------- prep: query transpose + (x,y,z,|p|^2) + zero stats ----------------
__global__ __launch_bounds__(256) void k_prep(const float* __restrict__ xyz_i,
                                              const float* __restrict__ xyz_last,
                                              float* __restrict__ xyzT,
                                              float4* __restrict__ xyzp,
                                              float* __restrict__ stats_zero) {
  int t = blockIdx.x * 256 + threadIdx.x;   // 8192 threads
  {
    float x = xyz_i[t * 3 + 0], y = xyz_i[t * 3 + 1], z = xyz_i[t * 3 + 2];
    xyzp[t] = make_float4(x, y, z, fmaf(x, x, fmaf(y, y, z * z)));
    xyzT[3 * NPTS + t] = xyz_last[t * 3 + 0];
    xyzT[4 * NPTS + t] = xyz_last[t * 3 + 1];
    xyzT[5 * NPTS + t] = xyz_last[t * 3 + 2];
  }
  if (t < 4864) stats_zero[t] = 0.f;
}

// ---------------- projections via MFMA: Out = A @ W^T + b (8192x128 @ 128x128) ----------------
// Same verified fragment pattern as k_mid: A-frag row=lane&15, k=(lane>>4)*8+j;
// W staged in LDS bf16 with (p&7)<<4 XOR swizzle; C/D col=lane&15, row=(lane>>4)*4+reg.
__global__ __launch_bounds__(256) void k_proj(const float* __restrict__ fea_i,
                                              const float* __restrict__ fea_last,
                                              const float* __restrict__ Wq,
                                              const float* __restrict__ Wk,
                                              const float* __restrict__ Wv,
                                              const float* __restrict__ bq,
                                              const float* __restrict__ bk,
                                              const float* __restrict__ bv,
                                              float* __restrict__ Qo,
                                              float* __restrict__ Kpo,
                                              float* __restrict__ Vpo) {
  const int z = blockIdx.y;
  const float* A    = (z == 0) ? fea_last : fea_i;
  const float* W    = (z == 0) ? Wq : ((z == 1) ? Wk : Wv);
  const float* bias = (z == 0) ? bq : ((z == 1) ? bk : bv);
  float* Out        = (z == 0) ? Qo : ((z == 1) ? Kpo : Vpo);

  __shared__ unsigned short wl[128 * 128];   // 32 KB swizzled bf16 W
  const int t = threadIdx.x;
  const int lane = t & 63, w = t >> 6;

  #pragma unroll
  for (int i = 0; i < 8; ++i) {
    const int chunk = i * 256 + t;                // 2048 chunks of 8 c's
    const int p = chunk >> 4, cseg = chunk & 15;
    const float4 wa = *(const float4*)(W + (size_t)p * 128 + cseg * 8);
    const float4 wb = *(const float4*)(W + (size_t)p * 128 + cseg * 8 + 4);
    uint4 pk;
    pk.x = pack_bf2(wa.x, wa.y); pk.y = pack_bf2(wa.z, wa.w);
    pk.z = pack_bf2(wb.x, wb.y); pk.w = pack_bf2(wb.z, wb.w);
    *(uint4*)((char*)wl + p * 256 + ((cseg * 16) ^ ((p & 7) << 4))) = pk;
  }
  __syncthreads();

  const int rowtile = blockIdx.x * 64 + w * 16;
  const int kslot = lane & 15, kgrp = lane >> 4;
  const float* Arow = A + (size_t)(rowtile + kslot) * 128;

  f32x4 acc[8];
  #pragma unroll
  for (int tt = 0; tt < 8; ++tt) acc[tt] = (f32x4){0.f, 0.f, 0.f, 0.f};

  #pragma unroll
  for (int s = 0; s < 4; ++s) {
    const int c0 = s * 32 + kgrp * 8;
    const float4 qa = *(const float4*)(Arow + c0);
    const float4 qb = *(const float4*)(Arow + c0 + 4);
    uint4 af;
    af.x = pack_bf2(qa.x, qa.y); af.y = pack_bf2(qa.z, qa.w);
    af.z = pack_bf2(qb.x, qb.y); af.w = pack_bf2(qb.z, qb.w);
    const bf16x8 Af = __builtin_bit_cast(bf16x8, af);
    const int cbyte = s * 64 + kgrp * 16;
    #pragma unroll
    for (int tt = 0; tt < 8; ++tt) {
      const int prow = tt * 16 + kslot;
      const uint4 bw = *(const uint4*)((const char*)wl + prow * 256 + (cbyte ^ ((prow & 7) << 4)));
      acc[tt] = __builtin_amdgcn_mfma_f32_16x16x32_bf16(Af, __builtin_bit_cast(bf16x8, bw), acc[tt], 0, 0, 0);
    }
  }

  #pragma unroll
  for (int tt = 0; tt < 8; ++tt) {
    const int col = tt * 16 + kslot;
    const float bb = bias[col];
    #pragma unroll
    for (int r = 0; r < 4; ++r) {
      const int row = rowtile + kgrp * 4 + r;
      Out[(size_t)row * 128 + col] = acc[tt][r] + bb;
    }
  }
}

// ---------------- fused KNN: ballot-append gate -> f32-head tournament ----------------
// One wave per query (4/block, 2048 blocks -> 100% occupancy headroom). Scan: 64 lanes
// stream all 8192 points (L2-resident float4), gated candidates appended deterministically
// via ballot+prefix-popc into a wave-private LDS pool. Extraction: per-lane sorted u64
// slice (len<=7); 16 rounds of wave-min on the f32 DISTANCE head only (6 b32 shuffles vs
// 12 for u64; NaN sentinel loses under IEEE minNum fminf); winner idx broadcast by
// ballot+readlane (0 DS); exact dist ties (rare) resolved by a min-idx butterfly -- lex
// (dist,idx) order preserved exactly. n<16 or overflow -> exact full-scan fallback.
__global__ __launch_bounds__(256) void k_knn(const float* __restrict__ xyzT,
                                             const float4* __restrict__ xyzp,
                                             int* __restrict__ idxo) {
  __shared__ unsigned long long pool[QPB][CAPQ];   // 4*408*8 = 13056 B
  const int t = threadIdx.x;
  const int lane = t & 63, wave = t >> 6;
  const int q = blockIdx.x * QPB + wave;

  const float qx = xyzT[3 * NPTS + q];
  const float qy = xyzT[4 * NPTS + q];
  const float qz = xyzT[5 * NPTS + q];
  int cnt = 0;

  const unsigned long long below = (1ull << lane) - 1ull;
  #pragma unroll 2
  for (int it = 0; it < NPTS / 64; ++it) {
    const int p = it * 64 + lane;
    const float4 pp = xyzp[p];
    float dx = qx - pp.x, dy = qy - pp.y, dz = qz - pp.z;
    float dd = fmaf(dx, dx, fmaf(dy, dy, dz * dz));   // exact reference-ordering formula
    bool g = dd < KNN_T2;
    unsigned long long mask = __ballot(g);
    int pos = cnt + (int)__popcll(mask & below);
    if (g && pos < CAPQ)
      pool[wave][pos] = ((unsigned long long)__float_as_uint(dd) << 32) | (unsigned int)p;
    cnt += (int)__popcll(mask);
  }
  // no __syncthreads: pool region is wave-private; in-wave DS ordering suffices

  if (cnt >= 16 && cnt <= CAPQ) {
    // per-lane sorted slice: positions {lane, lane+64, ...}, len <= ceil(408/64)=7
    unsigned long long lst[7];
    #pragma unroll
    for (int j = 0; j < 7; ++j) lst[j] = ~0ull;
    for (int j = lane; j < cnt; j += 64) {
      unsigned long long kk = pool[wave][j];
      #pragma unroll
      for (int u = 6; u >= 1; --u) {
        bool cm1 = kk < lst[u - 1];
        bool cs  = kk < lst[u];
        lst[u] = cm1 ? lst[u - 1] : (cs ? kk : lst[u]);
      }
      lst[0] = (kk < lst[0]) ? kk : lst[0];
    }
    int myidx = 0;
    #pragma unroll 1
    for (int r = 0; r < 16; ++r) {
      const float hd = __uint_as_float((unsigned int)(lst[0] >> 32));  // empty -> NaN, loses
      float wm = hd;
      #pragma unroll
      for (int o = 32; o; o >>= 1) wm = fminf(wm, __shfl_xor(wm, o));
      bool iswin = (hd == wm);                       // false for NaN heads
      const unsigned long long wmask = __ballot(iswin);
      unsigned int widx;
      if (__popcll(wmask) > 1) {
        // exact dist tie across lanes: lex tie-break by min idx
        unsigned int mi = iswin ? (unsigned int)lst[0] : 0xffffffffu;
        #pragma unroll
        for (int o = 32; o; o >>= 1) {
          unsigned int u = (unsigned int)__shfl_xor((int)mi, o);
          mi = (u < mi) ? u : mi;
        }
        widx = mi;
        iswin = iswin && ((unsigned int)lst[0] == mi);
      } else {
        const int wl = (int)__builtin_ctzll(wmask);
        widx = (unsigned int)__builtin_amdgcn_readlane((int)(unsigned int)lst[0], wl);
      }
      #pragma unroll
      for (int j = 0; j < 6; ++j) lst[j] = iswin ? lst[j + 1] : lst[j];
      lst[6] = iswin ? ~0ull : lst[6];
      if (lane == r) myidx = (int)widx;
    }
    if (lane < 16) idxo[q * 16 + lane] = myidx;
  } else {
    // exact fallback: per-lane top-16 over its 128 points, then 16 u64 wave-min rounds
    unsigned long long key[16];
    #pragma unroll
    for (int j = 0; j < 16; ++j) key[j] = ~0ull;
    for (int it = 0; it < NPTS / 64; ++it) {
      const int p = it * 64 + lane;
      const float4 pp = xyzp[p];
      float dx = qx - pp.x, dy = qy - pp.y, dz = qz - pp.z;
      float dd = fmaf(dx, dx, fmaf(dy, dy, dz * dz));
      insert16(key, ((unsigned long long)__float_as_uint(dd) << 32) | (unsigned int)p);
    }
    unsigned long long myout = ~0ull;
    #pragma unroll 1
    for (int r = 0; r < 16; ++r) {
      unsigned long long w = key[0];
      #pragma unroll
      for (int o = 32; o; o >>= 1) {
        unsigned long long u = __shfl_xor(w, o);
        w = (u < w) ? u : w;
      }
      if (key[0] == w) {
        #pragma unroll
        for (int j = 0; j < 15; ++j) key[j] = key[j + 1];
        key[15] = ~0ull;
      }
      if (lane == r) myout = w;
    }
    if (lane < 16) idxo[q * 16 + lane] = (int)(myout & 0xffffffffull);
  }
}

// ---------------- stats1: per-channel sum/sumsq of w = Q[n] - Kp[idx] ----------------
__global__ __launch_bounds__(256) void k_stats1(const float* __restrict__ Q,
                                                const float* __restrict__ Kp,
                                                const int* __restrict__ idx,
                                                float* __restrict__ stats1) {
  const int t = threadIdx.x;
  const int o = t & 127, h = t >> 7;
  float s = 0.f, q2 = 0.f;
  const int base = blockIdx.x * 512;
  for (int i = 0; i < 256; ++i) {
    const int row = base + i * 2 + h;
    const int n = row >> 4;
    const int pid = idx[row];
    float w = Q[(size_t)n * 128 + o] - Kp[(size_t)pid * 128 + o];
    s += w; q2 += w * w;
  }
  __shared__ float rs[256], rq[256];
  rs[t] = s; rq[t] = q2;
  __syncthreads();
  if (t < 128) {
    atomicAdd(&stats1[o],       rs[t] + rs[t + 128]);
    atomicAdd(&stats1[128 + o], rq[t] + rq[t + 128]);
  }
}

// ---------------- BN finalize: scale/shift from (sum,sumsq) ----------------
__global__ void k_bnfin(const float* __restrict__ stats, int nrep, float invM,
                        const float* __restrict__ gamma, const float* __restrict__ beta,
                        float* __restrict__ bn) {
  const int o = threadIdx.x;  // 128
  float s = 0.f, q = 0.f;
  for (int r = 0; r < nrep; ++r) { s += stats[r * 256 + o]; q += stats[r * 256 + 128 + o]; }
  float mean = s * invM;
  float var  = fmaf(-mean, mean, q * invM);     // biased variance
  float sc = gamma[o] * rsqrtf(var + BN_EPS);
  bn[o]       = sc;
  bn[128 + o] = fmaf(-mean, sc, beta[o]);
}

// ---------------- mid GEMM via MFMA: y = leaky(bn1(Q[n]-Kp[idx])) @ Wl^T + bl ----------------
__global__ __launch_bounds__(256) void k_mid(const float* __restrict__ Q,
                                             const float* __restrict__ Kp,
                                             const int* __restrict__ idx,
                                             const float* __restrict__ Wl,
                                             const float* __restrict__ bl,
                                             const float* __restrict__ bn1,
                                             float* __restrict__ stats2,
                                             unsigned short* __restrict__ Y) {
  __shared__ union {
    unsigned short wl[128 * 128];                 // 32 KB swizzled bf16 Wl
    struct {
      unsigned short stage[64][136];              // 17408 B Y staging (272B rows, 16B-aligned)
      float red[4 * 256];                         // 4 KB per-wave stats partials
    } ep;
  } sm;

  const int t = threadIdx.x;
  const int lane = t & 63, w = t >> 6;
  const int rowbase = blockIdx.x * 64;

  // stage Wl (f32 [p][c] row-major) -> LDS bf16, 16B chunks, XOR-swizzled
  #pragma unroll
  for (int i = 0; i < 8; ++i) {
    const int chunk = i * 256 + t;                // 2048 chunks of 8 c's
    const int p = chunk >> 4, cseg = chunk & 15;
    const float4 wa = *(const float4*)(Wl + (size_t)p * 128 + cseg * 8);
    const float4 wb = *(const float4*)(Wl + (size_t)p * 128 + cseg * 8 + 4);
    uint4 pk;
    pk.x = pack_bf2(wa.x, wa.y); pk.y = pack_bf2(wa.z, wa.w);
    pk.z = pack_bf2(wb.x, wb.y); pk.w = pack_bf2(wb.z, wb.w);
    *(uint4*)((char*)sm.wl + p * 256 + ((cseg * 16) ^ ((p & 7) << 4))) = pk;
  }
  __syncthreads();

  const int n = blockIdx.x * 4 + w;
  const int kslot = lane & 15;      // A row (neighbor slot) / B col within tile
  const int kgrp  = lane >> 4;      // k-group 0..3
  const int pid = idx[n * 16 + kslot];
  const float* Qrow = Q + (size_t)n * 128;
  const float* Krow = Kp + (size_t)pid * 128;

  f32x4 acc[8];
  #pragma unroll
  for (int tt = 0; tt < 8; ++tt) acc[tt] = (f32x4){0.f, 0.f, 0.f, 0.f};

  #pragma unroll
  for (int s = 0; s < 4; ++s) {
    const int c0 = s * 32 + kgrp * 8;
    const float4 qa = *(const float4*)(Qrow + c0);
    const float4 qb = *(const float4*)(Qrow + c0 + 4);
    const float4 ka = *(const float4*)(Krow + c0);
    const float4 kb = *(const float4*)(Krow + c0 + 4);
    const float4 sa = *(const float4*)(bn1 + c0);
    const float4 sb = *(const float4*)(bn1 + c0 + 4);
    const float4 ha = *(const float4*)(bn1 + 128 + c0);
    const float4 hb = *(const float4*)(bn1 + 128 + c0 + 4);
    float x[8];
    x[0] = fmaf(qa.x - ka.x, sa.x, ha.x);
    x[1] = fmaf(qa.y - ka.y, sa.y, ha.y);
    x[2] = fmaf(qa.z - ka.z, sa.z, ha.z);
    x[3] = fmaf(qa.w - ka.w, sa.w, ha.w);
    x[4] = fmaf(qb.x - kb.x, sb.x, hb.x);
    x[5] = fmaf(qb.y - kb.y, sb.y, hb.y);
    x[6] = fmaf(qb.z - kb.z, sb.z, hb.z);
    x[7] = fmaf(qb.w - kb.w, sb.w, hb.w);
    uint4 af;
    af.x = pack_bf2(fmaxf(x[0], SLOPE * x[0]), fmaxf(x[1], SLOPE * x[1]));
    af.y = pack_bf2(fmaxf(x[2], SLOPE * x[2]), fmaxf(x[3], SLOPE * x[3]));
    af.z = pack_bf2(fmaxf(x[4], SLOPE * x[4]), fmaxf(x[5], SLOPE * x[5]));
    af.w = pack_bf2(fmaxf(x[6], SLOPE * x[6]), fmaxf(x[7], SLOPE * x[7]));
    const bf16x8 A = __builtin_bit_cast(bf16x8, af);
    const int cbyte = s * 64 + kgrp * 16;
    #pragma unroll
    for (int tt = 0; tt < 8; ++tt) {
      const int prow = tt * 16 + kslot;
      const uint4 bw = *(const uint4*)((const char*)sm.wl + prow * 256 + (cbyte ^ ((prow & 7) << 4)));
      acc[tt] = __builtin_amdgcn_mfma_f32_16x16x32_bf16(A, __builtin_bit_cast(bf16x8, bw), acc[tt], 0, 0, 0);
    }
  }
  __syncthreads();   // all waves done reading sm.wl -> safe to reuse as ep

  // bias + per-col stats + bf16 staging
  #pragma unroll
  for (int tt = 0; tt < 8; ++tt) {
    const int col = tt * 16 + kslot;
    const float bb = bl[col];
    float s = 0.f, q2 = 0.f;
    #pragma unroll
    for (int r = 0; r < 4; ++r) {
      const float v = acc[tt][r] + bb;
      s += v; q2 += v * v;
      sm.ep.stage[w * 16 + kgrp * 4 + r][col] = bf1(v);
    }
    s  += __shfl_xor(s, 16);  s  += __shfl_xor(s, 32);
    q2 += __shfl_xor(q2, 16); q2 += __shfl_xor(q2, 32);
    if (kgrp == 0) {
      sm.ep.red[w * 256 + col]       = s;
      sm.ep.red[w * 256 + 128 + col] = q2;
    }
  }
  __syncthreads();

  // cooperative coalesced Y store (16B per thread per iter)
  #pragma unroll
  for (int i = 0; i < 4; ++i) {
    const int chunk = i * 256 + t;                // 1024 chunks
    const int row = chunk >> 4, cc = chunk & 15;
    const uint4 v = *(const uint4*)&sm.ep.stage[row][cc * 8];
    *(uint4*)&Y[(size_t)(rowbase + row) * 128 + cc * 8] = v;
  }
  // block stats2 reduction: t = stat*128 + col
  {
    const float tot = sm.ep.red[t] + sm.ep.red[256 + t] + sm.ep.red[512 + t] + sm.ep.red[768 + t];
    atomicAdd(&stats2[(blockIdx.x & 15) * 256 + t], tot);
  }
}

// ---------------- epilogue: BN2+leaky -> softmax over K -> weighted V gather ----------------
__global__ __launch_bounds__(128) void k_epi(const unsigned short* __restrict__ Y,
                                             const float* __restrict__ Vp,
                                             const int* __restrict__ idx,
                                             const float* __restrict__ bn2,
                                             float* __restrict__ out) {
  const int n = blockIdx.x;
  const int p = threadIdx.x;
  const float s2 = bn2[p], sh2 = bn2[128 + p];
  float z[16];
  #pragma unroll
  for (int k = 0; k < 16; ++k) {
    float yv = bf2f(Y[(size_t)(n * 16 + k) * 128 + p]);
    float v = fmaf(yv, s2, sh2);
    z[k] = (v >= 0.f) ? v : SLOPE * v;
  }
  float m = z[0];
  #pragma unroll
  for (int k = 1; k < 16; ++k) m = fmaxf(m, z[k]);
  float acc = 0.f, denom = 0.f;
  #pragma unroll
  for (int k = 0; k < 16; ++k) {
    float e = __expf(z[k] - m);
    denom += e;
    const int pid = idx[n * 16 + k];
    acc = fmaf(e, Vp[(size_t)pid * 128 + p], acc);
  }
  out[(size_t)n * 128 + p] = acc / denom;
}

extern "C" void kernel_launch(void* const* d_in, const int* in_sizes, int n_in,
                              void* d_out, int out_size, void* d_ws, size_t ws_size,
                              hipStream_t stream) {
  const float* fea_i    = (const float*)d_in[0];
  const float* fea_last = (const float*)d_in[1];
  const float* xyz_i    = (const float*)d_in[2];
  const float* xyz_last = (const float*)d_in[3];
  // d_in[4] = batch (single batch, unused)
  const float* Wq = (const float*)d_in[5];
  const float* bq = (const float*)d_in[6];
  const float* Wk = (const float*)d_in[7];
  const float* bk = (const float*)d_in[8];
  const float* Wv = (const float*)d_in[9];
  const float* bv = (const float*)d_in[10];
  const float* g1 = (const float*)d_in[11];
  const float* b1 = (const float*)d_in[12];
  const float* Wl = (const float*)d_in[13];
  const float* bl = (const float*)d_in[14];
  const float* g2 = (const float*)d_in[15];
  const float* b2 = (const float*)d_in[16];

  if (ws_size < (size_t)WS_NEED) return;

  char* ws = (char*)d_ws;
  float*  Q      = (float*)(ws + OFF_Q);
  float*  Kp     = (float*)(ws + OFF_KP);
  float*  Vp     = (float*)(ws + OFF_VP);
  float*  xyzT   = (float*)(ws + OFF_XYZT);
  int*    idxb   = (int*)  (ws + OFF_IDX);
  float*  stats1 = (float*)(ws + OFF_STATS);
  float*  bn1    = stats1 + 256;
  float*  stats2 = stats1 + 512;
  float*  bn2    = stats1 + 512 + 4096;
  float4* xyzp   = (float4*)(ws + OFF_BIG);             // dead after k_knn
  unsigned short* Y = (unsigned short*)(ws + OFF_BIG);  // aliases xyzp (k_mid runs after k_knn)

  k_prep<<<32, 256, 0, stream>>>(xyz_i, xyz_last, xyzT, xyzp, stats1);
  k_proj<<<dim3(128, 3), 256, 0, stream>>>(fea_i, fea_last, Wq, Wk, Wv, bq, bk, bv, Q, Kp, Vp);
  k_knn<<<NPTS / QPB, 256, 0, stream>>>(xyzT, xyzp, idxb);
  k_stats1<<<256, 256, 0, stream>>>(Q, Kp, idxb, stats1);
  k_bnfin<<<1, 128, 0, stream>>>(stats1, 1, 1.f / (float)NROWS, g1, b1, bn1);
  k_mid<<<2048, 256, 0, stream>>>(Q, Kp, idxb, Wl, bl, bn1, stats2, Y);
  k_bnfin<<<1, 128, 0, stream>>>(stats2, 16, 1.f / (float)NROWS, g2, b2, bn2);
  k_epi<<<8192, 128, 0, stream>>>(Y, Vp, idxb, bn2, (float*)d_out);
}

// Round 9
// 125.586 us; speedup vs baseline: 4.9825x; 1.4617x over previous
//
#include <hip/hip_runtime.h>
#include <stdint.h>

#define NPTS   8192
#define NROWS  (NPTS * 16)
#define SLOPE  0.01f
#define BN_EPS 1e-5f

// fused KNN parameters
#define KNN_T2 0.04f   // gate radius T=0.2 ; corner-query d16 ~ 0.155 -> 2.1x volume margin
#define CAPQ   408     // per-query candidate pool cap (lambda<=275, +8 sigma); overflow -> exact fallback
#define QPB    8       // queries per block (256 thr = 4 waves x 2 queries) -> 1024 blocks
#define QPW    2       // queries per wave (amortizes point loads)

// ---- workspace layout (bytes) ----
#define OFF_Q      0u          // 8192x128 f32  (fea_last @ Wq^T + bq)
#define OFF_KP     4194304u    // 8192x128 f32
#define OFF_VP     8388608u    // 8192x128 f32
#define OFF_STATS  12582912u   // 8704 f32: st1[16*256] st2[16*256] bn1[256] bn2[256] (old WT hole)
#define OFF_XYZT   12845056u   // 6 x 8192 f32 (only 3..5 used: query coords)
#define OFF_IDX    13041664u   // 131072 i32 (8192 x 16 neighbor ids)
#define OFF_BIG    13585408u   // xyzp (128KB, dead after knn), later aliased by Y bf16 (33.5MB)
#define WS_NEED    47139840u

typedef __bf16 bf16x8 __attribute__((ext_vector_type(8)));
typedef float  f32x4  __attribute__((ext_vector_type(4)));

__device__ __forceinline__ unsigned int pack_bf2(float lo, float hi) {
  unsigned int a = __float_as_uint(lo);
  unsigned int b = __float_as_uint(hi);
  unsigned int ra = (a + 0x7fffu + ((a >> 16) & 1u)) >> 16;           // RNE bf16 of lo
  unsigned int rb = (b + 0x7fffu + ((b >> 16) & 1u)) & 0xffff0000u;   // RNE bf16 of hi in high half
  return ra | rb;
}
__device__ __forceinline__ unsigned short bf1(float v) {
  unsigned int a = __float_as_uint(v);
  return (unsigned short)((a + 0x7fffu + ((a >> 16) & 1u)) >> 16);
}
__device__ __forceinline__ float bf2f(unsigned short u) {
  return __uint_as_float(((unsigned int)u) << 16);
}

__device__ __forceinline__ void insert16(unsigned long long* key, unsigned long long kk) {
  if (kk < key[15]) {
    #pragma unroll
    for (int u = 15; u >= 1; --u) {
      bool cm1 = kk < key[u - 1];
      bool cs  = kk < key[u];
      key[u] = cm1 ? key[u - 1] : (cs ? kk : key[u]);
    }
    key[0] = (kk < key[0]) ? kk : key[0];
  }
}

// ---------------- prep: query coords + (x,y,z,|p|^2) + zero stats slots ----------------
__global__ __launch_bounds__(256) void k_prep(const float* __restrict__ xyz_i,
                                              const float* __restrict__ xyz_last,
                                              float* __restrict__ xyzT,
                                              float4* __restrict__ xyzp,
                                              float* __restrict__ stats_zero) {
  int t = blockIdx.x * 256 + threadIdx.x;   // 8192 threads
  {
    float x = xyz_i[t * 3 + 0], y = xyz_i[t * 3 + 1], z = xyz_i[t * 3 + 2];
    xyzp[t] = make_float4(x, y, z, fmaf(x, x, fmaf(y, y, z * z)));
    xyzT[3 * NPTS + t] = xyz_last[t * 3 + 0];
    xyzT[4 * NPTS + t] = xyz_last[t * 3 + 1];
    xyzT[5 * NPTS + t] = xyz_last[t * 3 + 2];
  }
  stats_zero[t] = 0.f;   // st1[4096] + st2[4096] = exactly 8192
}

// ---------------- projections via MFMA: Out = A @ W^T + b (8192x128 @ 128x128) ----------------
__global__ __launch_bounds__(256) void k_proj(const float* __restrict__ fea_i,
                                              const float* __restrict__ fea_last,
                                              const float* __restrict__ Wq,
                                              const float* __restrict__ Wk,
                                              const float* __restrict__ Wv,
                                              const float* __restrict__ bq,
                                              const float* __restrict__ bk,
                                              const float* __restrict__ bv,
                                              float* __restrict__ Qo,
                                              float* __restrict__ Kpo,
                                              float* __restrict__ Vpo) {
  const int z = blockIdx.y;
  const float* A    = (z == 0) ? fea_last : fea_i;
  const float* W    = (z == 0) ? Wq : ((z == 1) ? Wk : Wv);
  const float* bias = (z == 0) ? bq : ((z == 1) ? bk : bv);
  float* Out        = (z == 0) ? Qo : ((z == 1) ? Kpo : Vpo);

  __shared__ unsigned short wl[128 * 128];   // 32 KB swizzled bf16 W
  const int t = threadIdx.x;
  const int lane = t & 63, w = t >> 6;

  #pragma unroll
  for (int i = 0; i < 8; ++i) {
    const int chunk = i * 256 + t;
    const int p = chunk >> 4, cseg = chunk & 15;
    const float4 wa = *(const float4*)(W + (size_t)p * 128 + cseg * 8);
    const float4 wb = *(const float4*)(W + (size_t)p * 128 + cseg * 8 + 4);
    uint4 pk;
    pk.x = pack_bf2(wa.x, wa.y); pk.y = pack_bf2(wa.z, wa.w);
    pk.z = pack_bf2(wb.x, wb.y); pk.w = pack_bf2(wb.z, wb.w);
    *(uint4*)((char*)wl + p * 256 + ((cseg * 16) ^ ((p & 7) << 4))) = pk;
  }
  __syncthreads();

  const int rowtile = blockIdx.x * 64 + w * 16;
  const int kslot = lane & 15, kgrp = lane >> 4;
  const float* Arow = A + (size_t)(rowtile + kslot) * 128;

  f32x4 acc[8];
  #pragma unroll
  for (int tt = 0; tt < 8; ++tt) acc[tt] = (f32x4){0.f, 0.f, 0.f, 0.f};

  #pragma unroll
  for (int s = 0; s < 4; ++s) {
    const int c0 = s * 32 + kgrp * 8;
    const float4 qa = *(const float4*)(Arow + c0);
    const float4 qb = *(const float4*)(Arow + c0 + 4);
    uint4 af;
    af.x = pack_bf2(qa.x, qa.y); af.y = pack_bf2(qa.z, qa.w);
    af.z = pack_bf2(qb.x, qb.y); af.w = pack_bf2(qb.z, qb.w);
    const bf16x8 Af = __builtin_bit_cast(bf16x8, af);
    const int cbyte = s * 64 + kgrp * 16;
    #pragma unroll
    for (int tt = 0; tt < 8; ++tt) {
      const int prow = tt * 16 + kslot;
      const uint4 bw = *(const uint4*)((const char*)wl + prow * 256 + (cbyte ^ ((prow & 7) << 4)));
      acc[tt] = __builtin_amdgcn_mfma_f32_16x16x32_bf16(Af, __builtin_bit_cast(bf16x8, bw), acc[tt], 0, 0, 0);
    }
  }

  #pragma unroll
  for (int tt = 0; tt < 8; ++tt) {
    const int col = tt * 16 + kslot;
    const float bb = bias[col];
    #pragma unroll
    for (int r = 0; r < 4; ++r) {
      const int row = rowtile + kgrp * 4 + r;
      Out[(size_t)row * 128 + col] = acc[tt][r] + bb;
    }
  }
}

// ---------------- fused KNN + stats1 ----------------
// Scan: block stages 512-point LDS tiles (register-prefetched next tile -> HBM/L2 latency
// hides under current-tile compute); each wave gates 2 queries per point, ballot-appends
// candidates to wave-private LDS pools. Extraction: per-lane sorted u64 slices (<=7);
// 16 rounds of f32-distance-head wave-min butterfly; winner idx via ballot+readlane;
// exact dist ties by min-idx butterfly (lex (dist,idx) order exact). Tail: with the 16
// neighbor ids in LDS, each lane accumulates BN1 sum/sumsq for its 2 channels over the
// 16 gathered rows (Q/Kp L2-resident), 4-wave LDS reduce, slotted global atomics.
__global__ __launch_bounds__(256) void k_knn(const float* __restrict__ xyzT,
                                             const float4* __restrict__ xyzp,
                                             const float* __restrict__ Q,
                                             const float* __restrict__ Kp,
                                             int* __restrict__ idxo,
                                             float* __restrict__ st1) {
  __shared__ float4 tile[512];                     // 8 KB point tile
  __shared__ unsigned long long pool[QPB][CAPQ];   // 26112 B
  __shared__ int sidx[4][QPW][16];                 // 512 B
  __shared__ float red[4][256];                    // 4 KB stats partials
  const int t = threadIdx.x;
  const int lane = t & 63, wave = t >> 6;
  const int qq0 = wave * QPW;
  const int qbase = blockIdx.x * QPB + qq0;

  float qx[QPW], qy[QPW], qz[QPW];
  #pragma unroll
  for (int i = 0; i < QPW; ++i) {
    qx[i] = xyzT[3 * NPTS + qbase + i];
    qy[i] = xyzT[4 * NPTS + qbase + i];
    qz[i] = xyzT[5 * NPTS + qbase + i];
  }
  int cnt[QPW];
  #pragma unroll
  for (int i = 0; i < QPW; ++i) cnt[i] = 0;
  const unsigned long long below = (1ull << lane) - 1ull;

  float4 pf0 = xyzp[t], pf1 = xyzp[t + 256];       // prefetch tile 0
  for (int tb = 0; tb < 16; ++tb) {
    tile[t] = pf0; tile[t + 256] = pf1;
    __syncthreads();
    if (tb < 15) {                                  // issue next-tile loads early (T14)
      pf0 = xyzp[(tb + 1) * 512 + t];
      pf1 = xyzp[(tb + 1) * 512 + t + 256];
    }
    const int pbase = tb * 512;
    #pragma unroll 2
    for (int it = 0; it < 8; ++it) {
      const float4 pp = tile[it * 64 + lane];
      const int p = pbase + it * 64 + lane;
      #pragma unroll
      for (int i = 0; i < QPW; ++i) {
        float dx = qx[i] - pp.x, dy = qy[i] - pp.y, dz = qz[i] - pp.z;
        float dd = fmaf(dx, dx, fmaf(dy, dy, dz * dz));   // exact reference-ordering formula
        bool g = dd < KNN_T2;
        unsigned long long mask = __ballot(g);
        int pos = cnt[i] + (int)__popcll(mask & below);
        if (g && pos < CAPQ)
          pool[qq0 + i][pos] = ((unsigned long long)__float_as_uint(dd) << 32) | (unsigned int)p;
        cnt[i] += (int)__popcll(mask);
      }
    }
    __syncthreads();   // tile reused next iteration
  }

  #pragma unroll 1
  for (int i = 0; i < QPW; ++i) {
    const int qq = qq0 + i;
    const int q = qbase + i;
    const int n = cnt[i];
    if (n >= 16 && n <= CAPQ) {
      unsigned long long lst[7];
      #pragma unroll
      for (int j = 0; j < 7; ++j) lst[j] = ~0ull;
      for (int j = lane; j < n; j += 64) {
        unsigned long long kk = pool[qq][j];
        #pragma unroll
        for (int u = 6; u >= 1; --u) {
          bool cm1 = kk < lst[u - 1];
          bool cs  = kk < lst[u];
          lst[u] = cm1 ? lst[u - 1] : (cs ? kk : lst[u]);
        }
        lst[0] = (kk < lst[0]) ? kk : lst[0];
      }
      int myidx = 0;
      #pragma unroll 1
      for (int r = 0; r < 16; ++r) {
        const float hd = __uint_as_float((unsigned int)(lst[0] >> 32));  // empty -> NaN, loses
        float wm = hd;
        #pragma unroll
        for (int o = 32; o; o >>= 1) wm = fminf(wm, __shfl_xor(wm, o));
        bool iswin = (hd == wm);                       // false for NaN heads
        const unsigned long long wmask = __ballot(iswin);
        unsigned int widx;
        if (__popcll(wmask) > 1) {
          unsigned int mi = iswin ? (unsigned int)lst[0] : 0xffffffffu;
          #pragma unroll
          for (int o = 32; o; o >>= 1) {
            unsigned int u = (unsigned int)__shfl_xor((int)mi, o);
            mi = (u < mi) ? u : mi;
          }
          widx = mi;
          iswin = iswin && ((unsigned int)lst[0] == mi);
        } else {
          const int wl = (int)__builtin_ctzll(wmask);
          widx = (unsigned int)__builtin_amdgcn_readlane((int)(unsigned int)lst[0], wl);
        }
        #pragma unroll
        for (int j = 0; j < 6; ++j) lst[j] = iswin ? lst[j + 1] : lst[j];
        lst[6] = iswin ? ~0ull : lst[6];
        if (lane == r) myidx = (int)widx;
      }
      if (lane < 16) {
        idxo[q * 16 + lane] = myidx;
        sidx[wave][i][lane] = myidx;
      }
    } else {
      // exact fallback: per-lane top-16 over its 128 points, then 16 u64 wave-min rounds
      unsigned long long key[16];
      #pragma unroll
      for (int j = 0; j < 16; ++j) key[j] = ~0ull;
      for (int it = 0; it < NPTS / 64; ++it) {
        const int p = it * 64 + lane;
        const float4 pp = xyzp[p];
        float dx = qx[i] - pp.x, dy = qy[i] - pp.y, dz = qz[i] - pp.z;
        float dd = fmaf(dx, dx, fmaf(dy, dy, dz * dz));
        insert16(key, ((unsigned long long)__float_as_uint(dd) << 32) | (unsigned int)p);
      }
      unsigned long long myout = ~0ull;
      #pragma unroll 1
      for (int r = 0; r < 16; ++r) {
        unsigned long long w = key[0];
        #pragma unroll
        for (int o = 32; o; o >>= 1) {
          unsigned long long u = __shfl_xor(w, o);
          w = (u < w) ? u : w;
        }
        if (key[0] == w) {
          #pragma unroll
          for (int j = 0; j < 15; ++j) key[j] = key[j + 1];
          key[15] = ~0ull;
        }
        if (lane == r) myout = w;
      }
      if (lane < 16) {
        idxo[q * 16 + lane] = (int)(myout & 0xffffffffull);
        sidx[wave][i][lane] = (int)(myout & 0xffffffffull);
      }
    }
  }

  // ---- fused BN1 stats: lane owns channels 2*lane, 2*lane+1 ----
  const int c0 = lane * 2;
  float s0 = 0.f, s1 = 0.f, v0 = 0.f, v1 = 0.f;
  #pragma unroll
  for (int i = 0; i < QPW; ++i) {
    const int q = qbase + i;
    const float2 qv = *(const float2*)(Q + (size_t)q * 128 + c0);
    #pragma unroll 4
    for (int k = 0; k < 16; ++k) {
      const int pid = sidx[wave][i][k];
      const float2 kv = *(const float2*)(Kp + (size_t)pid * 128 + c0);
      const float w0 = qv.x - kv.x, w1 = qv.y - kv.y;
      s0 += w0; v0 += w0 * w0;
      s1 += w1; v1 += w1 * w1;
    }
  }
  red[wave][c0]       = s0;  red[wave][c0 + 1]       = s1;
  red[wave][128 + c0] = v0;  red[wave][129 + c0]     = v1;
  __syncthreads();
  {
    const float tot = red[0][t & 255] + red[1][t & 255] + red[2][t & 255] + red[3][t & 255];
    atomicAdd(&st1[(blockIdx.x & 15) * 256 + (t & 255)], tot);
  }
}

// ---------------- BN finalize: scale/shift from slotted (sum,sumsq) ----------------
__global__ void k_bnfin(const float* __restrict__ stats, int nrep, float invM,
                        const float* __restrict__ gamma, const float* __restrict__ beta,
                        float* __restrict__ bn) {
  const int o = threadIdx.x;  // 128
  float s = 0.f, q = 0.f;
  for (int r = 0; r < nrep; ++r) { s += stats[r * 256 + o]; q += stats[r * 256 + 128 + o]; }
  float mean = s * invM;
  float var  = fmaf(-mean, mean, q * invM);     // biased variance
  float sc = gamma[o] * rsqrtf(var + BN_EPS);
  bn[o]       = sc;
  bn[128 + o] = fmaf(-mean, sc, beta[o]);
}

// ---------------- mid GEMM via MFMA: y = leaky(bn1(Q[n]-Kp[idx])) @ Wl^T + bl ----------------
__global__ __launch_bounds__(256) void k_mid(const float* __restrict__ Q,
                                             const float* __restrict__ Kp,
                                             const int* __restrict__ idx,
                                             const float* __restrict__ Wl,
                                             const float* __restrict__ bl,
                                             const float* __restrict__ bn1,
                                             float* __restrict__ stats2,
                                             unsigned short* __restrict__ Y) {
  __shared__ union {
    unsigned short wl[128 * 128];                 // 32 KB swizzled bf16 Wl
    struct {
      unsigned short stage[64][136];              // Y staging
      float red[4 * 256];                         // per-wave stats partials
    } ep;
  } sm;

  const int t = threadIdx.x;
  const int lane = t & 63, w = t >> 6;
  const int rowbase = blockIdx.x * 64;

  #pragma unroll
  for (int i = 0; i < 8; ++i) {
    const int chunk = i * 256 + t;
    const int p = chunk >> 4, cseg = chunk & 15;
    const float4 wa = *(const float4*)(Wl + (size_t)p * 128 + cseg * 8);
    const float4 wb = *(const float4*)(Wl + (size_t)p * 128 + cseg * 8 + 4);
    uint4 pk;
    pk.x = pack_bf2(wa.x, wa.y); pk.y = pack_bf2(wa.z, wa.w);
    pk.z = pack_bf2(wb.x, wb.y); pk.w = pack_bf2(wb.z, wb.w);
    *(uint4*)((char*)sm.wl + p * 256 + ((cseg * 16) ^ ((p & 7) << 4))) = pk;
  }
  __syncthreads();

  const int n = blockIdx.x * 4 + w;
  const int kslot = lane & 15;
  const int kgrp  = lane >> 4;
  const int pid = idx[n * 16 + kslot];
  const float* Qrow = Q + (size_t)n * 128;
  const float* Krow = Kp + (size_t)pid * 128;

  f32x4 acc[8];
  #pragma unroll
  for (int tt = 0; tt < 8; ++tt) acc[tt] = (f32x4){0.f, 0.f, 0.f, 0.f};

  #pragma unroll
  for (int s = 0; s < 4; ++s) {
    const int c0 = s * 32 + kgrp * 8;
    const float4 qa = *(const float4*)(Qrow + c0);
    const float4 qb = *(const float4*)(Qrow + c0 + 4);
    const float4 ka = *(const float4*)(Krow + c0);
    const float4 kb = *(const float4*)(Krow + c0 + 4);
    const float4 sa = *(const float4*)(bn1 + c0);
    const float4 sb = *(const float4*)(bn1 + c0 + 4);
    const float4 ha = *(const float4*)(bn1 + 128 + c0);
    const float4 hb = *(const float4*)(bn1 + 128 + c0 + 4);
    float x[8];
    x[0] = fmaf(qa.x - ka.x, sa.x, ha.x);
    x[1] = fmaf(qa.y - ka.y, sa.y, ha.y);
    x[2] = fmaf(qa.z - ka.z, sa.z, ha.z);
    x[3] = fmaf(qa.w - ka.w, sa.w, ha.w);
    x[4] = fmaf(qb.x - kb.x, sb.x, hb.x);
    x[5] = fmaf(qb.y - kb.y, sb.y, hb.y);
    x[6] = fmaf(qb.z - kb.z, sb.z, hb.z);
    x[7] = fmaf(qb.w - kb.w, sb.w, hb.w);
    uint4 af;
    af.x = pack_bf2(fmaxf(x[0], SLOPE * x[0]), fmaxf(x[1], SLOPE * x[1]));
    af.y = pack_bf2(fmaxf(x[2], SLOPE * x[2]), fmaxf(x[3], SLOPE * x[3]));
    af.z = pack_bf2(fmaxf(x[4], SLOPE * x[4]), fmaxf(x[5], SLOPE * x[5]));
    af.w = pack_bf2(fmaxf(x[6], SLOPE * x[6]), fmaxf(x[7], SLOPE * x[7]));
    const bf16x8 A = __builtin_bit_cast(bf16x8, af);
    const int cbyte = s * 64 + kgrp * 16;
    #pragma unroll
    for (int tt = 0; tt < 8; ++tt) {
      const int prow = tt * 16 + kslot;
      const uint4 bw = *(const uint4*)((const char*)sm.wl + prow * 256 + (cbyte ^ ((prow & 7) << 4)));
      acc[tt] = __builtin_amdgcn_mfma_f32_16x16x32_bf16(A, __builtin_bit_cast(bf16x8, bw), acc[tt], 0, 0, 0);
    }
  }
  __syncthreads();

  #pragma unroll
  for (int tt = 0; tt < 8; ++tt) {
    const int col = tt * 16 + kslot;
    const float bb = bl[col];
    float s = 0.f, q2 = 0.f;
    #pragma unroll
    for (int r = 0; r < 4; ++r) {
      const float v = acc[tt][r] + bb;
      s += v; q2 += v * v;
      sm.ep.stage[w * 16 + kgrp * 4 + r][col] = bf1(v);
    }
    s  += __shfl_xor(s, 16);  s  += __shfl_xor(s, 32);
    q2 += __shfl_xor(q2, 16); q2 += __shfl_xor(q2, 32);
    if (kgrp == 0) {
      sm.ep.red[w * 256 + col]       = s;
      sm.ep.red[w * 256 + 128 + col] = q2;
    }
  }
  __syncthreads();

  #pragma unroll
  for (int i = 0; i < 4; ++i) {
    const int chunk = i * 256 + t;
    const int row = chunk >> 4, cc = chunk & 15;
    const uint4 v = *(const uint4*)&sm.ep.stage[row][cc * 8];
    *(uint4*)&Y[(size_t)(rowbase + row) * 128 + cc * 8] = v;
  }
  {
    const float tot = sm.ep.red[t] + sm.ep.red[256 + t] + sm.ep.red[512 + t] + sm.ep.red[768 + t];
    atomicAdd(&stats2[(blockIdx.x & 15) * 256 + t], tot);
  }
}

// ---------------- epilogue: BN2+leaky -> softmax over K -> weighted V gather ----------------
__global__ __launch_bounds__(128) void k_epi(const unsigned short* __restrict__ Y,
                                             const float* __restrict__ Vp,
                                             const int* __restrict__ idx,
                                             const float* __restrict__ bn2,
                                             float* __restrict__ out) {
  const int n = blockIdx.x;
  const int p = threadIdx.x;
  const float s2 = bn2[p], sh2 = bn2[128 + p];
  float z[16];
  #pragma unroll
  for (int k = 0; k < 16; ++k) {
    float yv = bf2f(Y[(size_t)(n * 16 + k) * 128 + p]);
    float v = fmaf(yv, s2, sh2);
    z[k] = (v >= 0.f) ? v : SLOPE * v;
  }
  float m = z[0];
  #pragma unroll
  for (int k = 1; k < 16; ++k) m = fmaxf(m, z[k]);
  float acc = 0.f, denom = 0.f;
  #pragma unroll
  for (int k = 0; k < 16; ++k) {
    float e = __expf(z[k] - m);
    denom += e;
    const int pid = idx[n * 16 + k];
    acc = fmaf(e, Vp[(size_t)pid * 128 + p], acc);
  }
  out[(size_t)n * 128 + p] = acc / denom;
}

extern "C" void kernel_launch(void* const* d_in, const int* in_sizes, int n_in,
                              void* d_out, int out_size, void* d_ws, size_t ws_size,
                              hipStream_t stream) {
  const float* fea_i    = (const float*)d_in[0];
  const float* fea_last = (const float*)d_in[1];
  const float* xyz_i    = (const float*)d_in[2];
  const float* xyz_last = (const float*)d_in[3];
  // d_in[4] = batch (single batch, unused)
  const float* Wq = (const float*)d_in[5];
  const float* bq = (const float*)d_in[6];
  const float* Wk = (const float*)d_in[7];
  const float* bk = (const float*)d_in[8];
  const float* Wv = (const float*)d_in[9];
  const float* bv = (const float*)d_in[10];
  const float* g1 = (const float*)d_in[11];
  const float* b1 = (const float*)d_in[12];
  const float* Wl = (const float*)d_in[13];
  const float* bl = (const float*)d_in[14];
  const float* g2 = (const float*)d_in[15];
  const float* b2 = (const float*)d_in[16];

  if (ws_size < (size_t)WS_NEED) return;

  char* ws = (char*)d_ws;
  float*  Q      = (float*)(ws + OFF_Q);
  float*  Kp     = (float*)(ws + OFF_KP);
  float*  Vp     = (float*)(ws + OFF_VP);
  float*  xyzT   = (float*)(ws + OFF_XYZT);
  int*    idxb   = (int*)  (ws + OFF_IDX);
  float*  st1    = (float*)(ws + OFF_STATS);            // [16*256]
  float*  st2    = st1 + 4096;                          // [16*256]
  float*  bn1    = st1 + 8192;                          // [256]
  float*  bn2    = st1 + 8448;                          // [256]
  float4* xyzp   = (float4*)(ws + OFF_BIG);             // dead after k_knn
  unsigned short* Y = (unsigned short*)(ws + OFF_BIG);  // aliases xyzp (k_mid runs after k_knn)

  k_prep<<<32, 256, 0, stream>>>(xyz_i, xyz_last, xyzT, xyzp, st1);
  k_proj<<<dim3(128, 3), 256, 0, stream>>>(fea_i, fea_last, Wq, Wk, Wv, bq, bk, bv, Q, Kp, Vp);
  k_knn<<<NPTS / QPB, 256, 0, stream>>>(xyzT, xyzp, Q, Kp, idxb, st1);
  k_bnfin<<<1, 128, 0, stream>>>(st1, 16, 1.f / (float)NROWS, g1, b1, bn1);
  k_mid<<<2048, 256, 0, stream>>>(Q, Kp, idxb, Wl, bl, bn1, st2, Y);
  k_bnfin<<<1, 128, 0, stream>>>(st2, 16, 1.f / (float)NROWS, g2, b2, bn2);
  k_epi<<<8192, 128, 0, stream>>>(Y, Vp, idxb, bn2, (float*)d_out);
}